// Round 6
// baseline (985.272 us; speedup 1.0000x reference)
//
#include <hip/hip_runtime.h>

#define EPS 1e-5f

typedef __attribute__((ext_vector_type(4))) _Float16 h4;
typedef __attribute__((ext_vector_type(8))) _Float16 h8;
typedef __attribute__((ext_vector_type(4))) float f4;

// ---- workspace float offsets (stats region; zeroed by prep0) ----
#define WS_SB1        0
#define WS_SB2        128
#define WS_STAT_C1    256
#define WS_STAT_QKV0  384
#define WS_STAT_QKV1  640
#define WS_STAT_SIM0  896
#define WS_STAT_SIM1  928
#define WS_STAT_OUT0  960
#define WS_STAT_OUT1  1216
#define WS_STAT_C2    1472
#define WS_STAT_END   1600

// ---- buffer regions (float offsets) ----
#define WS_R1  4096
#define WS_R2  (WS_R1 + 8388608)
#define WS_R3  (WS_R2 + 8388608)

// ---- pass-kernel LDS byte offsets (80 KiB -> 2 blocks/CU) ----
#define L_QEA 0        // [128 y][128 x] fp16 swz ^((y&7)<<4); later P[i][j]; later sred
#define L_KEB 32768    // k_emb same; later Pd halves
#define L_RET 65536    // build: re [256 d][16 c] swz ^((d&4)<<2); later ve [16 c][256 d] swz ^((c&7)<<4)
#define L_AQ  73728    // q [128 a][16 c]; later V [16 c][128 j] swz ^((c&7)<<4)
#define L_AK  77824    // k rows 8-15; passA: f32 red[] scratch
#define L_V   73728

__device__ __forceinline__ float wred(float v) {
    #pragma unroll
    for (int off = 32; off > 0; off >>= 1) v += __shfl_down(v, off, 64);
    return v;
}

__global__ void k_prep0(const float* __restrict__ lin1, const float* __restrict__ lin2,
                        const float* __restrict__ latent, float* __restrict__ ws) {
    int t = threadIdx.x;
    for (int i = 256 + t; i < WS_STAT_END; i += 256) ws[i] = 0.f;
    const float* lin = (t < 128) ? lin1 : lin2;
    int row = t & 127;
    float s = 0.f;
    for (int l = 0; l < 256; ++l) s += lin[row * 256 + l] * latent[l];
    ws[(t < 128 ? WS_SB1 : WS_SB2) + row] = s;
}

// conv1 + fused per-channel stats
__global__ __launch_bounds__(256) void k_conv1(const float* __restrict__ in,
                                               const float* __restrict__ w,
                                               float* __restrict__ out,
                                               float* __restrict__ stat) {
    __shared__ float ws_[4096];
    int t = threadIdx.x;
    int lane = t & 63;
    for (int i = t; i < 4096; i += 256) ws_[i] = w[i];
    __syncthreads();
    int p  = blockIdx.x * 256 + t;
    int b  = p >> 14, hw = p & 16383;
    const float* ip = in + b * 64 * 16384 + hw;
    float x[64];
    #pragma unroll
    for (int c = 0; c < 64; ++c) x[c] = ip[c * 16384];
    float* op = out + b * 64 * 16384 + hw;
    for (int o = 0; o < 64; ++o) {
        float acc = 0.f;
        #pragma unroll
        for (int c = 0; c < 64; ++c) acc += ws_[o * 64 + c] * x[c];
        op[o * 16384] = acc;
        float s = wred(acc), ss = wred(acc * acc);
        if (lane == 0) { atomicAdd(&stat[o], s); atomicAdd(&stat[64 + o], ss); }
    }
}

// f32 per-channel stats over [M][C][K] (used for c2o only)
__global__ void k_stats(const float* __restrict__ src, int C, int logK, int MK, int split,
                        float* __restrict__ stat) {
    int c = blockIdx.x % C;
    int chunk = blockIdx.x / C;
    int per = MK / split;
    int base = chunk * per;
    int Km1 = (1 << logK) - 1;
    float s = 0.f, ss = 0.f;
    for (int i = base + threadIdx.x; i < base + per; i += blockDim.x) {
        int m = i >> logK, k = i & Km1;
        float v = src[((m * C + c) << logK) + k];
        s += v; ss += v * v;
    }
    s = wred(s); ss = wred(ss);
    if ((threadIdx.x & 63) == 0) { atomicAdd(&stat[c], s); atomicAdd(&stat[C + c], ss); }
}

// out0[b][c][h][w] -> t1t[b][w][c][h], inline cbn1 coef + prelu
__global__ __launch_bounds__(256) void k_t1t(const float* __restrict__ src, float* __restrict__ dst,
                                             const float* __restrict__ ws,
                                             const float* __restrict__ g1,
                                             const float* __restrict__ b1,
                                             const float* __restrict__ prelu1) {
    __shared__ float tile[32][33];
    int bid = blockIdx.x;
    int wt = bid & 3, ht = (bid >> 2) & 3, c = (bid >> 4) & 63, b = bid >> 10;
    float mean = ws[WS_STAT_C1 + c] * (1.f / 65536.f);
    float var  = ws[WS_STAT_C1 + 64 + c] * (1.f / 65536.f) - mean * mean;
    float ab = g1[c] * rsqrtf(var + EPS);
    float sc = ws[WS_SB1 + c], bi = ws[WS_SB1 + 64 + c];
    float A = sc * ab;
    float Bb = sc * (b1[c] - mean * ab) + bi;
    float slope = *prelu1;
    int tx = threadIdx.x & 31, ty = threadIdx.x >> 5;
    const float* sp = src + ((b * 64 + c) * 128 + ht * 32) * 128 + wt * 32;
    for (int r = 0; r < 4; ++r) {
        float v = sp[(ty + r * 8) * 128 + tx];
        v = A * v + Bb;
        v = v >= 0.f ? v : slope * v;
        tile[ty + r * 8][tx] = v;
    }
    __syncthreads();
    float* dp = dst + b * 1048576 + (wt * 32) * 8192 + c * 128 + ht * 32;
    for (int r = 0; r < 4; ++r)
        dp[(ty + r * 8) * 8192 + tx] = tile[tx][ty + r * 8];
}

// MFMA qkv GEMM: out[o][a] = sum_c w[o][c] * x(b,r,c,a); fp16 out + fused stats
__global__ __launch_bounds__(256) void k_qkvm(const float* __restrict__ x, const float* __restrict__ w,
                                              _Float16* __restrict__ out, float* __restrict__ statq,
                                              int SB, int SR, int SC) {
    __shared__ __align__(16) _Float16 Wh[8192];   // [o][c ^ ((o&7)<<3)]
    __shared__ __align__(16) _Float16 Xt[8192];   // [a][c ^ ((a&7)<<3)]
    int t = threadIdx.x;
    int lane = t & 63, wv = t >> 6;
    int l15 = lane & 15, g4 = lane >> 4;
    int n = blockIdx.x;
    int b = n >> 7, r = n & 127;
    for (int i = t; i < 8192; i += 256) {
        int o = i >> 6, c = i & 63;
        Wh[o * 64 + (c ^ ((o & 7) << 3))] = (_Float16)w[i];
    }
    const float* xp = x + b * SB + r * SR;
    for (int i = t; i < 8192; i += 256) {
        int c = i >> 7, a = i & 127;
        Xt[a * 64 + (c ^ ((a & 7) << 3))] = (_Float16)xp[c * SC + a];
    }
    __syncthreads();
    f4 acc[2][8];
    #pragma unroll
    for (int ot2 = 0; ot2 < 2; ++ot2) {
        int orow = (wv * 2 + ot2) * 16 + l15;
        h8 af[2];
        #pragma unroll
        for (int kk = 0; kk < 2; ++kk)
            af[kk] = *(const h8*)&Wh[orow * 64 + ((kk * 32 + g4 * 8) ^ ((orow & 7) << 3))];
        #pragma unroll
        for (int at = 0; at < 8; ++at) {
            int arow = at * 16 + l15;
            f4 c4 = {0.f, 0.f, 0.f, 0.f};
            #pragma unroll
            for (int kk = 0; kk < 2; ++kk) {
                h8 bf = *(const h8*)&Xt[arow * 64 + ((kk * 32 + g4 * 8) ^ ((arow & 7) << 3))];
                c4 = __builtin_amdgcn_mfma_f32_16x16x32_f16(af[kk], bf, c4, 0, 0, 0);
            }
            acc[ot2][at] = c4;
        }
    }
    _Float16* op = out + n * 16384;
    #pragma unroll
    for (int ot2 = 0; ot2 < 2; ++ot2) {
        #pragma unroll
        for (int r4 = 0; r4 < 4; ++r4) {
            int o = (wv * 2 + ot2) * 16 + g4 * 4 + r4;
            float s = 0.f, ss = 0.f;
            #pragma unroll
            for (int at = 0; at < 8; ++at) {
                float v = acc[ot2][at][r4];
                op[o * 128 + at * 16 + l15] = (_Float16)v;
                s += v; ss += v * v;
            }
            #pragma unroll
            for (int msk = 1; msk < 16; msk <<= 1) {
                s += __shfl_xor(s, msk, 64); ss += __shfl_xor(ss, msk, 64);
            }
            if (l15 == 0) { atomicAdd(&statq[o], s); atomicAdd(&statq[128 + o], ss); }
        }
    }
}

// ---- pass helpers (512 threads) ----
__device__ __forceinline__ void stage_aqk(unsigned char* L, const _Float16* qkv,
                                          const float* statq, const float* qg, const float* qb,
                                          int n, int g, int t) {
    const _Float16* qp = qkv + n * 16384 + g * 32 * 128;
    #pragma unroll
    for (int k = 0; k < 4; ++k) {
        int i = t + k * 512;
        int a = i & 127, cc = i >> 7;
        int ch = g * 32 + cc;
        float mean = statq[ch] * (1.f / 65536.f);
        float var  = statq[128 + ch] * (1.f / 65536.f) - mean * mean;
        float A = qg[ch] * rsqrtf(var + EPS);
        float B = qb[ch] - mean * A;
        float v = A * (float)qp[cc * 128 + a] + B;
        _Float16 h = (_Float16)v;
        int off = a * 32 + ((cc * 2) ^ ((a & 4) << 2));
        *(_Float16*)(L + L_AQ + off) = (cc < 8) ? h : (_Float16)0.f;
        *(_Float16*)(L + L_AK + off) = (cc < 8) ? (_Float16)0.f : h;
    }
}

__device__ __forceinline__ void stage_ret(unsigned char* L, const float* remb, int crow0, int t) {
    #pragma unroll
    for (int k = 0; k < 8; ++k) {
        int i = t + k * 512;
        int d = i & 255, c = i >> 8;
        float v = (d < 255) ? remb[(crow0 + c) * 255 + d] : 0.f;
        *(_Float16*)(L + L_RET + d * 32 + ((c * 2) ^ ((d & 4) << 2))) = (_Float16)v;
    }
}

template <bool STATS>
__device__ __forceinline__ void build_emb(unsigned char* L, int w, int l15, int g4, float* s) {
    int at = w;
    int arow = at * 16 + l15;
    int aoff = arow * 32 + ((g4 * 8) ^ ((arow & 4) << 2));
    h4 aq = *(const h4*)(L + L_AQ + aoff);
    h4 ak = *(const h4*)(L + L_AK + aoff);
    int abase = at * 16 + g4 * 4;
    #pragma unroll
    for (int m = 0; m < 9; ++m) {
        int drow = (at + m) * 16 + l15;
        h4 bf = *(const h4*)(L + L_RET + drow * 32 + ((g4 * 8) ^ ((drow & 4) << 2)));
        f4 z = {0.f, 0.f, 0.f, 0.f};
        f4 dq = __builtin_amdgcn_mfma_f32_16x16x16f16(aq, bf, z, 0, 0, 0);
        f4 dk = __builtin_amdgcn_mfma_f32_16x16x16f16(ak, bf, z, 0, 0, 0);
        #pragma unroll
        for (int r = 0; r < 4; ++r) {
            int a = abase + r;
            int b = 127 + a - drow;
            bool ok = (m == 0 || m == 8) ? (b >= 0 && b < 128) : true;
            if (ok) {
                int off = b * 256 + ((a * 2) ^ ((b & 7) << 4));
                *(_Float16*)(L + L_QEA + off) = (_Float16)dq[r];
                *(_Float16*)(L + L_KEB + off) = (_Float16)dk[r];
                if (STATS) {
                    s[0] += dq[r]; s[1] += dq[r] * dq[r];
                    s[2] += dk[r]; s[3] += dk[r] * dk[r];
                }
            }
        }
    }
}

__device__ __forceinline__ void qk_mfma(unsigned char* L, int i0, int l15, int g4, f4 acc[8]) {
    h8 af[4];
    #pragma unroll
    for (int ks = 0; ks < 4; ++ks) {
        int row = i0 + l15;
        af[ks] = *(const h8*)(L + L_QEA + row * 256 + ((ks * 64 + g4 * 16) ^ ((row & 7) << 4)));
    }
    #pragma unroll
    for (int tj = 0; tj < 8; ++tj) {
        h8 bf[4];
        #pragma unroll
        for (int ks = 0; ks < 4; ++ks) {
            int row = tj * 16 + l15;
            bf[ks] = *(const h8*)(L + L_KEB + row * 256 + ((ks * 64 + g4 * 16) ^ ((row & 7) << 4)));
        }
        f4 c = {0.f, 0.f, 0.f, 0.f};
        #pragma unroll
        for (int ks = 0; ks < 4; ++ks)
            c = __builtin_amdgcn_mfma_f32_16x16x32_f16(af[ks], bf[ks], c, 0, 0, 0);
        acc[tj] = c;
    }
}

__global__ __launch_bounds__(512, 4) void k_passA(const _Float16* __restrict__ qkv,
                                                  const float* __restrict__ remb,
                                                  const float* __restrict__ statq,
                                                  const float* __restrict__ qg,
                                                  const float* __restrict__ qb,
                                                  float* __restrict__ statsim) {
    __shared__ __align__(16) unsigned char L[81920];
    int t = threadIdx.x;
    int lane = t & 63, w = t >> 6;
    int l15 = lane & 15, g4 = lane >> 4;
    int n = blockIdx.x >> 2, g = blockIdx.x & 3;

    stage_aqk(L, qkv, statq, qg, qb, n, g, t);
    stage_ret(L, remb, 0, t);
    __syncthreads();

    float es[4] = {0.f, 0.f, 0.f, 0.f};
    build_emb<true>(L, w, l15, g4, es);
    __syncthreads();

    float* red = (float*)(L + L_AK);
    #pragma unroll
    for (int k = 0; k < 4; ++k) es[k] = wred(es[k]);
    if (lane == 0) {
        red[w * 4 + 0] = es[0]; red[w * 4 + 1] = es[1];
        red[w * 4 + 2] = es[2]; red[w * 4 + 3] = es[3];
    }

    f4 acc[8];
    qk_mfma(L, w * 16, l15, g4, acc);

    float s = 0.f, ss = 0.f;
    #pragma unroll
    for (int tj = 0; tj < 8; ++tj)
        #pragma unroll
        for (int r = 0; r < 4; ++r) { float x = acc[tj][r]; s += x; ss += x * x; }
    s = wred(s); ss = wred(ss);
    if (lane == 0) { red[32 + w * 2] = s; red[33 + w * 2] = ss; }
    __syncthreads();

    if (t < 6) {
        float v = 0.f;
        int dst;
        if (t == 0)      { for (int k = 0; k < 8; ++k) v += red[32 + 2 * k]; dst = g; }
        else if (t == 1) { for (int k = 0; k < 8; ++k) v += red[33 + 2 * k]; dst = 12 + g; }
        else if (t == 2) { for (int k = 0; k < 8; ++k) v += red[k * 4 + 0];  dst = 4 + g; }
        else if (t == 3) { for (int k = 0; k < 8; ++k) v += red[k * 4 + 1];  dst = 16 + g; }
        else if (t == 4) { for (int k = 0; k < 8; ++k) v += red[k * 4 + 2];  dst = 8 + g; }
        else             { for (int k = 0; k < 8; ++k) v += red[k * 4 + 3];  dst = 20 + g; }
        atomicAdd(&statsim[dst], v);
    }
}

// passB: rebuild, combine+softmax, am+ame MFMA, packed fp16 att, fused out-stats
__global__ __launch_bounds__(512, 4) void k_passB(const _Float16* __restrict__ qkv,
                                                  const float* __restrict__ remb,
                                                  const float* __restrict__ statq,
                                                  const float* __restrict__ qg,
                                                  const float* __restrict__ qb,
                                                  const float* __restrict__ statsim,
                                                  const float* __restrict__ simg,
                                                  const float* __restrict__ simb,
                                                  unsigned int* __restrict__ att2,
                                                  float* __restrict__ statout) {
    __shared__ __align__(16) unsigned char L[81920];
    int t = threadIdx.x;
    int lane = t & 63, w = t >> 6;
    int l15 = lane & 15, g4 = lane >> 4;
    int n = blockIdx.x >> 2, g = blockIdx.x & 3;

    stage_aqk(L, qkv, statq, qg, qb, n, g, t);
    stage_ret(L, remb, 0, t);
    __syncthreads();

    build_emb<false>(L, w, l15, g4, nullptr);
    __syncthreads();

    #pragma unroll
    for (int k = 0; k < 4; ++k) {
        int i = t + k * 512;
        int j = i & 127, c = i >> 7;
        int ch = g * 32 + 16 + c;
        float mean = statq[ch] * (1.f / 65536.f);
        float var  = statq[128 + ch] * (1.f / 65536.f) - mean * mean;
        float A = qg[ch] * rsqrtf(var + EPS);
        float B = qb[ch] - mean * A;
        float v = A * (float)qkv[n * 16384 + ch * 128 + j] + B;
        *(_Float16*)(L + L_V + c * 256 + ((j * 2) ^ ((c & 7) << 4))) = (_Float16)v;
    }
    #pragma unroll
    for (int k = 0; k < 8; ++k) {
        int i = t + k * 512;
        int d = i & 255, c = i >> 8;
        float v = (d < 255) ? remb[(16 + c) * 255 + d] : 0.f;
        *(_Float16*)(L + L_RET + c * 512 + ((d * 2) ^ ((c & 7) << 4))) = (_Float16)v;
    }

    int i0 = w * 16;
    f4 acc[8];
    qk_mfma(L, i0, l15, g4, acc);

    float Aqk, Aqe, Ake, Cst = 0.f;
    {
        float cnt = 1.f / 8388608.f;
        float A3[3];
        #pragma unroll
        for (int k = 0; k < 3; ++k) {
            int ch = k * 4 + g;
            float mean = statsim[ch] * cnt;
            float var  = statsim[12 + ch] * cnt - mean * mean;
            float A = simg[ch] * rsqrtf(var + EPS);
            A3[k] = A;
            Cst += simb[ch] - mean * A;
        }
        Aqk = A3[0]; Aqe = A3[1]; Ake = A3[2];
    }
    int ib = (i0 + g4 * 4) * 2;
    #pragma unroll
    for (int tj = 0; tj < 8; ++tj) {
        int j = tj * 16 + l15;
        h4 q4 = *(const h4*)(L + L_QEA + j * 256 + (ib ^ ((j & 7) << 4)));
        h4 k4 = *(const h4*)(L + L_KEB + j * 256 + (ib ^ ((j & 7) << 4)));
        #pragma unroll
        for (int r = 0; r < 4; ++r)
            acc[tj][r] = Aqk * acc[tj][r] + Aqe * (float)q4[r] + Ake * (float)k4[r] + Cst;
    }

    float inv4[4];
    #pragma unroll
    for (int r = 0; r < 4; ++r) {
        float m = acc[0][r];
        #pragma unroll
        for (int tj = 1; tj < 8; ++tj) m = fmaxf(m, acc[tj][r]);
        #pragma unroll
        for (int msk = 1; msk < 16; msk <<= 1) m = fmaxf(m, __shfl_xor(m, msk, 64));
        float s = 0.f;
        #pragma unroll
        for (int tj = 0; tj < 8; ++tj) {
            float e = __expf(acc[tj][r] - m);
            acc[tj][r] = e; s += e;
        }
        #pragma unroll
        for (int msk = 1; msk < 16; msk <<= 1) s += __shfl_xor(s, msk, 64);
        inv4[r] = 1.f / s;
    }
    __syncthreads();

    #pragma unroll
    for (int r = 0; r < 4; ++r) {
        int i = i0 + g4 * 4 + r;
        int swz = (i & 7) << 4;
        float inv = inv4[r];
        #pragma unroll
        for (int tj = 0; tj < 8; ++tj) {
            int j = tj * 16 + l15;
            _Float16 h = (_Float16)(acc[tj][r] * inv);
            *(_Float16*)(L + L_QEA + i * 256 + ((j * 2) ^ swz)) = h;
            int cl = (j >= i) ? (127 + i - j) : j;
            *(_Float16*)(L + L_KEB + i * 256 + ((cl * 2) ^ swz)) = (j >= i) ? h : (_Float16)0.f;
        }
    }
    __syncthreads();

    h8 vf[4], vef[4];
    #pragma unroll
    for (int ks = 0; ks < 4; ++ks) {
        vf[ks]  = *(const h8*)(L + L_V   + l15 * 256 + ((ks * 64 + g4 * 16) ^ ((l15 & 7) << 4)));
        vef[ks] = *(const h8*)(L + L_RET + l15 * 512 + ((ks * 64 + g4 * 16) ^ ((l15 & 7) << 4)));
    }
    int row = i0 + l15;
    int sw = (row & 7) << 4;
    f4 cam = {0.f, 0.f, 0.f, 0.f}, cae = {0.f, 0.f, 0.f, 0.f};
    #pragma unroll
    for (int ks = 0; ks < 4; ++ks) {
        h8 pf  = *(const h8*)(L + L_QEA + row * 256 + ((ks * 64 + g4 * 16) ^ sw));
        h8 plf = *(const h8*)(L + L_KEB + row * 256 + ((ks * 64 + g4 * 16) ^ sw));
        cam = __builtin_amdgcn_mfma_f32_16x16x32_f16(vf[ks],  pf,  cam, 0, 0, 0);
        cae = __builtin_amdgcn_mfma_f32_16x16x32_f16(vef[ks], plf, cae, 0, 0, 0);
    }
    __syncthreads();

    #pragma unroll
    for (int r = 0; r < 4; ++r) {
        int i = i0 + g4 * 4 + r;
        int swz = (i & 7) << 4;
        float inv = inv4[r];
        #pragma unroll
        for (int tj = 0; tj < 8; ++tj) {
            int j = tj * 16 + l15;
            _Float16 h = (_Float16)(acc[tj][r] * inv);
            int cl = (j < i) ? (i - 1 - j) : j;
            *(_Float16*)(L + L_KEB + i * 256 + ((cl * 2) ^ swz)) = (j < i) ? h : (_Float16)0.f;
        }
    }
    __syncthreads();

    h8 vef2[4];
    #pragma unroll
    for (int ks = 0; ks < 4; ++ks)
        vef2[ks] = *(const h8*)(L + L_RET + l15 * 512 + ((256 + ks * 64 + g4 * 16) ^ ((l15 & 7) << 4)));
    #pragma unroll
    for (int ks = 0; ks < 4; ++ks) {
        h8 phf = *(const h8*)(L + L_KEB + row * 256 + ((ks * 64 + g4 * 16) ^ sw));
        cae = __builtin_amdgcn_mfma_f32_16x16x32_f16(vef2[ks], phf, cae, 0, 0, 0);
    }

    // packed fp16 (am, ame) store: att2[n][g*16 + c][i]
    unsigned int* ab = att2 + n * 8192 + (g * 16) * 128;
    int i = i0 + l15;
    #pragma unroll
    for (int r = 0; r < 4; ++r) {
        int c = g4 * 4 + r;
        union { _Float16 h[2]; unsigned int u; } pk;
        pk.h[0] = (_Float16)cam[r];
        pk.h[1] = (_Float16)cae[r];
        ab[c * 128 + i] = pk.u;
    }

    // fused out-BN stats from f32 values
    float* sred = (float*)(L + L_QEA);
    #pragma unroll
    for (int r = 0; r < 4; ++r) {
        float sa = cam[r], qa = cam[r] * cam[r];
        float se = cae[r], qe = cae[r] * cae[r];
        #pragma unroll
        for (int msk = 1; msk < 16; msk <<= 1) {
            sa += __shfl_xor(sa, msk, 64); qa += __shfl_xor(qa, msk, 64);
            se += __shfl_xor(se, msk, 64); qe += __shfl_xor(qe, msk, 64);
        }
        if (l15 == 0) {
            int base = w * 64 + g4 * 16 + r * 4;
            sred[base + 0] = sa; sred[base + 1] = qa;
            sred[base + 2] = se; sred[base + 3] = qe;
        }
    }
    __syncthreads();
    if (t < 64) {
        int lc = t & 31, stat = t >> 5;
        int c = lc >> 1, s = lc & 1;
        int gg4 = c >> 2, r = c & 3;
        float v = 0.f;
        #pragma unroll
        for (int ww = 0; ww < 8; ++ww)
            v += sred[ww * 64 + gg4 * 16 + r * 4 + 2 * s + stat];
        atomicAdd(&statout[stat * 128 + g * 32 + lc], v);
    }
}

// axial0 finish: att2[n=b*128+w][p][h] u32 -> t2[b][c][h][w], BN + pair-sum
__global__ __launch_bounds__(256) void k_finish0(const unsigned int* __restrict__ att2,
                                                 const float* __restrict__ statout,
                                                 const float* __restrict__ og,
                                                 const float* __restrict__ ob,
                                                 float* __restrict__ t2) {
    __shared__ float tile[8][32][33];
    __shared__ float cf[256];
    int t = threadIdx.x;
    if (t < 128) {
        float mean = statout[t] * (1.f / 65536.f);
        float var  = statout[128 + t] * (1.f / 65536.f) - mean * mean;
        float A = og[t] * rsqrtf(var + EPS);
        cf[t] = A;
        cf[128 + t] = ob[t] - mean * A;
    }
    __syncthreads();
    int bid = blockIdx.x;
    int wt = bid & 3, ht = (bid >> 2) & 3, cg = (bid >> 4) & 7, b = bid >> 7;
    for (int i = t; i < 8192; i += 256) {
        int h = i & 31, w = (i >> 5) & 31, cl = i >> 10;
        int c_out = cg * 8 + cl;
        int chg = (c_out >> 4) * 32 + (c_out & 15) * 2;
        int p = chg >> 1;
        union { unsigned int u; _Float16 h2[2]; } pk;
        pk.u = att2[((b * 128 + wt * 32 + w) * 64 + p) * 128 + ht * 32 + h];
        tile[cl][w][h] = cf[chg] * (float)pk.h2[0] + cf[128 + chg]
                       + cf[chg + 1] * (float)pk.h2[1] + cf[129 + chg];
    }
    __syncthreads();
    for (int i = t; i < 8192; i += 256) {
        int w = i & 31, h = (i >> 5) & 31, cl = i >> 10;
        t2[((b * 64 + cg * 8 + cl) * 128 + ht * 32 + h) * 128 + wt * 32 + w] = tile[cl][w][h];
    }
}

// axial1 finish: att2[n=b*128+h][p][w] u32 -> t3[b][c][h][w]
__global__ __launch_bounds__(256) void k_finish1(const unsigned int* __restrict__ att2,
                                                 const float* __restrict__ statout,
                                                 const float* __restrict__ og,
                                                 const float* __restrict__ ob,
                                                 float* __restrict__ t3) {
    int idx = blockIdx.x * 256 + threadIdx.x;
    int w = idx & 127, h = (idx >> 7) & 127, c = (idx >> 14) & 63, b = idx >> 20;
    int p = (c >> 4) * 16 + (c & 15);
    int chg = 2 * p;
    float m0 = statout[chg] * (1.f / 65536.f);
    float v0_ = statout[128 + chg] * (1.f / 65536.f) - m0 * m0;
    float A0 = og[chg] * rsqrtf(v0_ + EPS);
    float B0 = ob[chg] - m0 * A0;
    float m1 = statout[chg + 1] * (1.f / 65536.f);
    float v1_ = statout[129 + chg] * (1.f / 65536.f) - m1 * m1;
    float A1 = og[chg + 1] * rsqrtf(v1_ + EPS);
    float B1 = ob[chg + 1] - m1 * A1;
    union { unsigned int u; _Float16 h2[2]; } pk;
    pk.u = att2[((b * 128 + h) * 64 + p) * 128 + w];
    t3[idx] = A0 * (float)pk.h2[0] + B0 + A1 * (float)pk.h2[1] + B1;
}

__global__ __launch_bounds__(256) void k_conv2(const float* __restrict__ t3,
                                               const float* __restrict__ w,
                                               float* __restrict__ out) {
    __shared__ float ws_[4096];
    int t = threadIdx.x;
    for (int i = t; i < 4096; i += 256) ws_[i] = w[i];
    __syncthreads();
    int p = blockIdx.x * 256 + t;
    int b = p >> 12, yx = p & 4095, y = yx >> 6, x = yx & 63;
    const float* tp = t3 + b * 1048576 + (2 * y) * 128 + 2 * x;
    float xc[64];
    #pragma unroll
    for (int c = 0; c < 64; ++c) {
        const float* q = tp + c * 16384;
        xc[c] = 0.25f * (q[0] + q[1] + q[128] + q[129]);
    }
    float* op = out + b * 262144 + yx;
    for (int o = 0; o < 64; ++o) {
        float acc = 0.f;
        #pragma unroll
        for (int c = 0; c < 64; ++c) acc += ws_[o * 64 + c] * xc[c];
        op[o * 4096] = acc;
    }
}

__global__ __launch_bounds__(256) void k_final(const float* __restrict__ c2out,
                                               const float* __restrict__ input,
                                               const float* __restrict__ ws,
                                               const float* __restrict__ g2,
                                               const float* __restrict__ b2,
                                               const float* __restrict__ prelu2,
                                               float* __restrict__ out) {
    int idx = blockIdx.x * 256 + threadIdx.x;
    int x = idx & 63, y = (idx >> 6) & 63, o = (idx >> 12) & 63, b = idx >> 18;
    float mean = ws[WS_STAT_C2 + o] * (1.f / 16384.f);
    float var  = ws[WS_STAT_C2 + 64 + o] * (1.f / 16384.f) - mean * mean;
    float ab = g2[o] * rsqrtf(var + EPS);
    float sc = ws[WS_SB2 + o], bi = ws[WS_SB2 + 64 + o];
    float A = sc * ab;
    float B = sc * (b2[o] - mean * ab) + bi;
    float v = A * c2out[idx] + B;
    const float* ip = input + ((b * 64 + o) * 128 + 2 * y) * 128 + 2 * x;
    v += 0.25f * (ip[0] + ip[1] + ip[128] + ip[129]);
    float s = *prelu2;
    out[idx] = v >= 0.f ? v : s * v;
}

extern "C" void kernel_launch(void* const* d_in, const int* in_sizes, int n_in,
                              void* d_out, int out_size, void* d_ws, size_t ws_size,
                              hipStream_t stream) {
    const float* input    = (const float*)d_in[0];
    const float* latent   = (const float*)d_in[1];
    const float* w_in     = (const float*)d_in[2];
    const float* cbn1_g   = (const float*)d_in[3];
    const float* cbn1_b   = (const float*)d_in[4];
    const float* cbn1_lin = (const float*)d_in[5];
    const float* prelu1   = (const float*)d_in[6];
    const float* ax_qkv_w[2] = {(const float*)d_in[7],  (const float*)d_in[15]};
    const float* ax_qkv_g[2] = {(const float*)d_in[8],  (const float*)d_in[16]};
    const float* ax_qkv_b[2] = {(const float*)d_in[9],  (const float*)d_in[17]};
    const float* ax_sim_g[2] = {(const float*)d_in[10], (const float*)d_in[18]};
    const float* ax_sim_b[2] = {(const float*)d_in[11], (const float*)d_in[19]};
    const float* ax_rel[2]   = {(const float*)d_in[12], (const float*)d_in[20]};
    const float* ax_out_g[2] = {(const float*)d_in[13], (const float*)d_in[21]};
    const float* ax_out_b[2] = {(const float*)d_in[14], (const float*)d_in[22]};
    const float* w_out    = (const float*)d_in[23];
    const float* cbn2_g   = (const float*)d_in[24];
    const float* cbn2_b   = (const float*)d_in[25];
    const float* cbn2_lin = (const float*)d_in[26];
    const float* prelu2   = (const float*)d_in[27];

    float* ws    = (float*)d_ws;
    float* out0  = ws + WS_R1;
    float* t1t   = ws + WS_R1 + 4194304;
    unsigned int* att2 = (unsigned int*)(ws + WS_R1);   // 16 MiB (lower half of R1)
    float* c2o   = ws + WS_R1;
    _Float16* qkvh = (_Float16*)(ws + WS_R2);
    float* t23   = ws + WS_R3;
    float* dst   = (float*)d_out;

    k_prep0<<<1, 256, 0, stream>>>(cbn1_lin, cbn2_lin, latent, ws);
    k_conv1<<<256, 256, 0, stream>>>(input, w_in, out0, ws + WS_STAT_C1);
    k_t1t<<<4096, 256, 0, stream>>>(out0, t1t, ws, cbn1_g, cbn1_b, prelu1);

    // axial 0 (n = b*128 + w, a = h)
    k_qkvm<<<512, 256, 0, stream>>>(t1t, ax_qkv_w[0], qkvh, ws + WS_STAT_QKV0,
                                    1048576, 8192, 128);
    k_passA<<<2048, 512, 0, stream>>>(qkvh, ax_rel[0], ws + WS_STAT_QKV0,
                                      ax_qkv_g[0], ax_qkv_b[0], ws + WS_STAT_SIM0);
    k_passB<<<2048, 512, 0, stream>>>(qkvh, ax_rel[0], ws + WS_STAT_QKV0,
                                      ax_qkv_g[0], ax_qkv_b[0], ws + WS_STAT_SIM0,
                                      ax_sim_g[0], ax_sim_b[0], att2, ws + WS_STAT_OUT0);
    k_finish0<<<512, 256, 0, stream>>>(att2, ws + WS_STAT_OUT0, ax_out_g[0], ax_out_b[0], t23);

    // axial 1 (n = b*128 + h, a = w)
    k_qkvm<<<512, 256, 0, stream>>>(t23, ax_qkv_w[1], qkvh, ws + WS_STAT_QKV1,
                                    1048576, 128, 16384);
    k_passA<<<2048, 512, 0, stream>>>(qkvh, ax_rel[1], ws + WS_STAT_QKV1,
                                      ax_qkv_g[1], ax_qkv_b[1], ws + WS_STAT_SIM1);
    k_passB<<<2048, 512, 0, stream>>>(qkvh, ax_rel[1], ws + WS_STAT_QKV1,
                                      ax_qkv_g[1], ax_qkv_b[1], ws + WS_STAT_SIM1,
                                      ax_sim_g[1], ax_sim_b[1], att2, ws + WS_STAT_OUT1);
    k_finish1<<<16384, 256, 0, stream>>>(att2, ws + WS_STAT_OUT1, ax_out_g[1], ax_out_b[1], t23);

    k_conv2<<<64, 256, 0, stream>>>(t23, w_out, c2o);
    k_stats<<<256, 256, 0, stream>>>(c2o, 64, 12, 16384, 4, ws + WS_STAT_C2);
    k_final<<<4096, 256, 0, stream>>>(c2o, input, ws, cbn2_g, cbn2_b, prelu2, dst);
}

// Round 7
// 413.485 us; speedup vs baseline: 2.3829x; 2.3829x over previous
//
#include <hip/hip_runtime.h>

#define EPS 1e-5f
#define SP 16   // stat padding stride: one float per 64B line

typedef __attribute__((ext_vector_type(4))) _Float16 h4;
typedef __attribute__((ext_vector_type(8))) _Float16 h8;
typedef __attribute__((ext_vector_type(4))) float f4;

// ---- workspace float offsets. Stat arrays are SP-strided (logical idx i at base + i*SP).
#define WS_SB1        0
#define WS_SB2        128
#define WS_STAT_C1    256        // 128 entries -> 2048
#define WS_STAT_QKV0  2304       // 256 -> 4096
#define WS_STAT_QKV1  6400       // 256 -> 4096
#define WS_STAT_SIM0  10496      // 24 -> 384
#define WS_STAT_SIM1  10880      // 24 -> 384
#define WS_STAT_OUT0  11264      // 256 -> 4096
#define WS_STAT_OUT1  15360      // 256 -> 4096
#define WS_STAT_C2    19456      // 128 -> 2048
#define WS_STAT_END   21504

// ---- buffer regions (float offsets) ----
#define WS_R1  32768
#define WS_R2  (WS_R1 + 8388608)
#define WS_R3  (WS_R2 + 8388608)

// ---- pass-kernel LDS byte offsets (80 KiB -> 2 blocks/CU) ----
#define L_QEA 0
#define L_KEB 32768
#define L_RET 65536
#define L_AQ  73728
#define L_AK  77824
#define L_V   73728

__device__ __forceinline__ float wred(float v) {
    #pragma unroll
    for (int off = 32; off > 0; off >>= 1) v += __shfl_down(v, off, 64);
    return v;
}

__global__ void k_prep0(const float* __restrict__ lin1, const float* __restrict__ lin2,
                        const float* __restrict__ latent, float* __restrict__ ws) {
    int t = threadIdx.x;
    for (int i = 256 + t; i < WS_STAT_END; i += 256) ws[i] = 0.f;
    const float* lin = (t < 128) ? lin1 : lin2;
    int row = t & 127;
    float s = 0.f;
    for (int l = 0; l < 256; ++l) s += lin[row * 256 + l] * latent[l];
    ws[(t < 128 ? WS_SB1 : WS_SB2) + row] = s;
}

// plain conv1 (stats separate — fused per-wave atomics proven catastrophic in R6)
__global__ __launch_bounds__(256) void k_conv1(const float* __restrict__ in,
                                               const float* __restrict__ w,
                                               float* __restrict__ out) {
    __shared__ float ws_[4096];
    int t = threadIdx.x;
    for (int i = t; i < 4096; i += 256) ws_[i] = w[i];
    __syncthreads();
    int p  = blockIdx.x * 256 + t;
    int b  = p >> 14, hw = p & 16383;
    const float* ip = in + b * 64 * 16384 + hw;
    float x[64];
    #pragma unroll
    for (int c = 0; c < 64; ++c) x[c] = ip[c * 16384];
    float* op = out + b * 64 * 16384 + hw;
    for (int o = 0; o < 64; ++o) {
        float acc = 0.f;
        #pragma unroll
        for (int c = 0; c < 64; ++c) acc += ws_[o * 64 + c] * x[c];
        op[o * 16384] = acc;
    }
}

// f32 per-channel stats over [M][C][K]; SP-strided output
__global__ void k_stats(const float* __restrict__ src, int C, int logK, int MK, int split,
                        float* __restrict__ stat) {
    int c = blockIdx.x % C;
    int chunk = blockIdx.x / C;
    int per = MK / split;
    int base = chunk * per;
    int Km1 = (1 << logK) - 1;
    float s = 0.f, ss = 0.f;
    for (int i = base + threadIdx.x; i < base + per; i += blockDim.x) {
        int m = i >> logK, k = i & Km1;
        float v = src[((m * C + c) << logK) + k];
        s += v; ss += v * v;
    }
    s = wred(s); ss = wred(ss);
    if ((threadIdx.x & 63) == 0) { atomicAdd(&stat[c * SP], s); atomicAdd(&stat[(C + c) * SP], ss); }
}

// fp16 per-channel stats; SP-strided output
__global__ void k_stats_h(const _Float16* __restrict__ src, int C, int logK, int MK, int split,
                          float* __restrict__ stat) {
    int c = blockIdx.x % C;
    int chunk = blockIdx.x / C;
    int per = MK / split;
    int base = chunk * per;
    int Km1 = (1 << logK) - 1;
    float s = 0.f, ss = 0.f;
    for (int i = base + threadIdx.x; i < base + per; i += blockDim.x) {
        int m = i >> logK, k = i & Km1;
        float v = (float)src[((m * C + c) << logK) + k];
        s += v; ss += v * v;
    }
    s = wred(s); ss = wred(ss);
    if ((threadIdx.x & 63) == 0) { atomicAdd(&stat[c * SP], s); atomicAdd(&stat[(C + c) * SP], ss); }
}

// out0[b][c][h][w] -> t1t[b][w][c][h], inline cbn1 coef + prelu
__global__ __launch_bounds__(256) void k_t1t(const float* __restrict__ src, float* __restrict__ dst,
                                             const float* __restrict__ ws,
                                             const float* __restrict__ g1,
                                             const float* __restrict__ b1,
                                             const float* __restrict__ prelu1) {
    __shared__ float tile[32][33];
    int bid = blockIdx.x;
    int wt = bid & 3, ht = (bid >> 2) & 3, c = (bid >> 4) & 63, b = bid >> 10;
    float mean = ws[WS_STAT_C1 + c * SP] * (1.f / 65536.f);
    float var  = ws[WS_STAT_C1 + (64 + c) * SP] * (1.f / 65536.f) - mean * mean;
    float ab = g1[c] * rsqrtf(var + EPS);
    float sc = ws[WS_SB1 + c], bi = ws[WS_SB1 + 64 + c];
    float A = sc * ab;
    float Bb = sc * (b1[c] - mean * ab) + bi;
    float slope = *prelu1;
    int tx = threadIdx.x & 31, ty = threadIdx.x >> 5;
    const float* sp = src + ((b * 64 + c) * 128 + ht * 32) * 128 + wt * 32;
    for (int r = 0; r < 4; ++r) {
        float v = sp[(ty + r * 8) * 128 + tx];
        v = A * v + Bb;
        v = v >= 0.f ? v : slope * v;
        tile[ty + r * 8][tx] = v;
    }
    __syncthreads();
    float* dp = dst + b * 1048576 + (wt * 32) * 8192 + c * 128 + ht * 32;
    for (int r = 0; r < 4; ++r)
        dp[(ty + r * 8) * 8192 + tx] = tile[tx][ty + r * 8];
}

// MFMA qkv GEMM: out[o][a] = sum_c w[o][c] * x(b,r,c,a); fp16 out (stats separate)
__global__ __launch_bounds__(256) void k_qkvm(const float* __restrict__ x, const float* __restrict__ w,
                                              _Float16* __restrict__ out,
                                              int SB, int SR, int SC) {
    __shared__ __align__(16) _Float16 Wh[8192];
    __shared__ __align__(16) _Float16 Xt[8192];
    int t = threadIdx.x;
    int lane = t & 63, wv = t >> 6;
    int l15 = lane & 15, g4 = lane >> 4;
    int n = blockIdx.x;
    int b = n >> 7, r = n & 127;
    for (int i = t; i < 8192; i += 256) {
        int o = i >> 6, c = i & 63;
        Wh[o * 64 + (c ^ ((o & 7) << 3))] = (_Float16)w[i];
    }
    const float* xp = x + b * SB + r * SR;
    for (int i = t; i < 8192; i += 256) {
        int c = i >> 7, a = i & 127;
        Xt[a * 64 + (c ^ ((a & 7) << 3))] = (_Float16)xp[c * SC + a];
    }
    __syncthreads();
    _Float16* op = out + n * 16384;
    #pragma unroll
    for (int ot2 = 0; ot2 < 2; ++ot2) {
        int orow = (wv * 2 + ot2) * 16 + l15;
        h8 af[2];
        #pragma unroll
        for (int kk = 0; kk < 2; ++kk)
            af[kk] = *(const h8*)&Wh[orow * 64 + ((kk * 32 + g4 * 8) ^ ((orow & 7) << 3))];
        #pragma unroll
        for (int at = 0; at < 8; ++at) {
            int arow = at * 16 + l15;
            f4 c4 = {0.f, 0.f, 0.f, 0.f};
            #pragma unroll
            for (int kk = 0; kk < 2; ++kk) {
                h8 bf = *(const h8*)&Xt[arow * 64 + ((kk * 32 + g4 * 8) ^ ((arow & 7) << 3))];
                c4 = __builtin_amdgcn_mfma_f32_16x16x32_f16(af[kk], bf, c4, 0, 0, 0);
            }
            #pragma unroll
            for (int r4 = 0; r4 < 4; ++r4) {
                int o = (wv * 2 + ot2) * 16 + g4 * 4 + r4;
                op[o * 128 + at * 16 + l15] = (_Float16)c4[r4];
            }
        }
    }
}

// ---- pass helpers (512 threads) ----
__device__ __forceinline__ void stage_aqk(unsigned char* L, const _Float16* qkv,
                                          const float* statq, const float* qg, const float* qb,
                                          int n, int g, int t) {
    const _Float16* qp = qkv + n * 16384 + g * 32 * 128;
    #pragma unroll
    for (int k = 0; k < 4; ++k) {
        int i = t + k * 512;
        int a = i & 127, cc = i >> 7;
        int ch = g * 32 + cc;
        float mean = statq[ch * SP] * (1.f / 65536.f);
        float var  = statq[(128 + ch) * SP] * (1.f / 65536.f) - mean * mean;
        float A = qg[ch] * rsqrtf(var + EPS);
        float B = qb[ch] - mean * A;
        float v = A * (float)qp[cc * 128 + a] + B;
        _Float16 h = (_Float16)v;
        int off = a * 32 + ((cc * 2) ^ ((a & 4) << 2));
        *(_Float16*)(L + L_AQ + off) = (cc < 8) ? h : (_Float16)0.f;
        *(_Float16*)(L + L_AK + off) = (cc < 8) ? (_Float16)0.f : h;
    }
}

__device__ __forceinline__ void stage_ret(unsigned char* L, const float* remb, int crow0, int t) {
    #pragma unroll
    for (int k = 0; k < 8; ++k) {
        int i = t + k * 512;
        int d = i & 255, c = i >> 8;
        float v = (d < 255) ? remb[(crow0 + c) * 255 + d] : 0.f;
        *(_Float16*)(L + L_RET + d * 32 + ((c * 2) ^ ((d & 4) << 2))) = (_Float16)v;
    }
}

template <bool STATS>
__device__ __forceinline__ void build_emb(unsigned char* L, int w, int l15, int g4, float* s) {
    int at = w;
    int arow = at * 16 + l15;
    int aoff = arow * 32 + ((g4 * 8) ^ ((arow & 4) << 2));
    h4 aq = *(const h4*)(L + L_AQ + aoff);
    h4 ak = *(const h4*)(L + L_AK + aoff);
    int abase = at * 16 + g4 * 4;
    #pragma unroll
    for (int m = 0; m < 9; ++m) {
        int drow = (at + m) * 16 + l15;
        h4 bf = *(const h4*)(L + L_RET + drow * 32 + ((g4 * 8) ^ ((drow & 4) << 2)));
        f4 z = {0.f, 0.f, 0.f, 0.f};
        f4 dq = __builtin_amdgcn_mfma_f32_16x16x16f16(aq, bf, z, 0, 0, 0);
        f4 dk = __builtin_amdgcn_mfma_f32_16x16x16f16(ak, bf, z, 0, 0, 0);
        #pragma unroll
        for (int r = 0; r < 4; ++r) {
            int a = abase + r;
            int b = 127 + a - drow;
            bool ok = (m == 0 || m == 8) ? (b >= 0 && b < 128) : true;
            if (ok) {
                int off = b * 256 + ((a * 2) ^ ((b & 7) << 4));
                *(_Float16*)(L + L_QEA + off) = (_Float16)dq[r];
                *(_Float16*)(L + L_KEB + off) = (_Float16)dk[r];
                if (STATS) {
                    s[0] += dq[r]; s[1] += dq[r] * dq[r];
                    s[2] += dk[r]; s[3] += dk[r] * dk[r];
                }
            }
        }
    }
}

__device__ __forceinline__ void qk_mfma(unsigned char* L, int i0, int l15, int g4, f4 acc[8]) {
    h8 af[4];
    #pragma unroll
    for (int ks = 0; ks < 4; ++ks) {
        int row = i0 + l15;
        af[ks] = *(const h8*)(L + L_QEA + row * 256 + ((ks * 64 + g4 * 16) ^ ((row & 7) << 4)));
    }
    #pragma unroll
    for (int tj = 0; tj < 8; ++tj) {
        h8 bf[4];
        #pragma unroll
        for (int ks = 0; ks < 4; ++ks) {
            int row = tj * 16 + l15;
            bf[ks] = *(const h8*)(L + L_KEB + row * 256 + ((ks * 64 + g4 * 16) ^ ((row & 7) << 4)));
        }
        f4 c = {0.f, 0.f, 0.f, 0.f};
        #pragma unroll
        for (int ks = 0; ks < 4; ++ks)
            c = __builtin_amdgcn_mfma_f32_16x16x32_f16(af[ks], bf[ks], c, 0, 0, 0);
        acc[tj] = c;
    }
}

__global__ __launch_bounds__(512, 4) void k_passA(const _Float16* __restrict__ qkv,
                                                  const float* __restrict__ remb,
                                                  const float* __restrict__ statq,
                                                  const float* __restrict__ qg,
                                                  const float* __restrict__ qb,
                                                  float* __restrict__ statsim) {
    __shared__ __align__(16) unsigned char L[81920];
    int t = threadIdx.x;
    int lane = t & 63, w = t >> 6;
    int l15 = lane & 15, g4 = lane >> 4;
    int n = blockIdx.x >> 2, g = blockIdx.x & 3;

    stage_aqk(L, qkv, statq, qg, qb, n, g, t);
    stage_ret(L, remb, 0, t);
    __syncthreads();

    float es[4] = {0.f, 0.f, 0.f, 0.f};
    build_emb<true>(L, w, l15, g4, es);
    __syncthreads();

    float* red = (float*)(L + L_AK);
    #pragma unroll
    for (int k = 0; k < 4; ++k) es[k] = wred(es[k]);
    if (lane == 0) {
        red[w * 4 + 0] = es[0]; red[w * 4 + 1] = es[1];
        red[w * 4 + 2] = es[2]; red[w * 4 + 3] = es[3];
    }

    f4 acc[8];
    qk_mfma(L, w * 16, l15, g4, acc);

    float s = 0.f, ss = 0.f;
    #pragma unroll
    for (int tj = 0; tj < 8; ++tj)
        #pragma unroll
        for (int r = 0; r < 4; ++r) { float x = acc[tj][r]; s += x; ss += x * x; }
    s = wred(s); ss = wred(ss);
    if (lane == 0) { red[32 + w * 2] = s; red[33 + w * 2] = ss; }
    __syncthreads();

    if (t < 6) {
        float v = 0.f;
        int dst;
        if (t == 0)      { for (int k = 0; k < 8; ++k) v += red[32 + 2 * k]; dst = g; }
        else if (t == 1) { for (int k = 0; k < 8; ++k) v += red[33 + 2 * k]; dst = 12 + g; }
        else if (t == 2) { for (int k = 0; k < 8; ++k) v += red[k * 4 + 0];  dst = 4 + g; }
        else if (t == 3) { for (int k = 0; k < 8; ++k) v += red[k * 4 + 1];  dst = 16 + g; }
        else if (t == 4) { for (int k = 0; k < 8; ++k) v += red[k * 4 + 2];  dst = 8 + g; }
        else             { for (int k = 0; k < 8; ++k) v += red[k * 4 + 3];  dst = 20 + g; }
        atomicAdd(&statsim[dst * SP], v);
    }
}

// passB: rebuild, combine+softmax, am+ame MFMA, packed fp16 att, fused out-stats (padded)
__global__ __launch_bounds__(512, 4) void k_passB(const _Float16* __restrict__ qkv,
                                                  const float* __restrict__ remb,
                                                  const float* __restrict__ statq,
                                                  const float* __restrict__ qg,
                                                  const float* __restrict__ qb,
                                                  const float* __restrict__ statsim,
                                                  const float* __restrict__ simg,
                                                  const float* __restrict__ simb,
                                                  unsigned int* __restrict__ att2,
                                                  float* __restrict__ statout) {
    __shared__ __align__(16) unsigned char L[81920];
    int t = threadIdx.x;
    int lane = t & 63, w = t >> 6;
    int l15 = lane & 15, g4 = lane >> 4;
    int n = blockIdx.x >> 2, g = blockIdx.x & 3;

    stage_aqk(L, qkv, statq, qg, qb, n, g, t);
    stage_ret(L, remb, 0, t);
    __syncthreads();

    build_emb<false>(L, w, l15, g4, nullptr);
    __syncthreads();

    #pragma unroll
    for (int k = 0; k < 4; ++k) {
        int i = t + k * 512;
        int j = i & 127, c = i >> 7;
        int ch = g * 32 + 16 + c;
        float mean = statq[ch * SP] * (1.f / 65536.f);
        float var  = statq[(128 + ch) * SP] * (1.f / 65536.f) - mean * mean;
        float A = qg[ch] * rsqrtf(var + EPS);
        float B = qb[ch] - mean * A;
        float v = A * (float)qkv[n * 16384 + ch * 128 + j] + B;
        *(_Float16*)(L + L_V + c * 256 + ((j * 2) ^ ((c & 7) << 4))) = (_Float16)v;
    }
    #pragma unroll
    for (int k = 0; k < 8; ++k) {
        int i = t + k * 512;
        int d = i & 255, c = i >> 8;
        float v = (d < 255) ? remb[(16 + c) * 255 + d] : 0.f;
        *(_Float16*)(L + L_RET + c * 512 + ((d * 2) ^ ((c & 7) << 4))) = (_Float16)v;
    }

    int i0 = w * 16;
    f4 acc[8];
    qk_mfma(L, i0, l15, g4, acc);

    float Aqk, Aqe, Ake, Cst = 0.f;
    {
        float cnt = 1.f / 8388608.f;
        float A3[3];
        #pragma unroll
        for (int k = 0; k < 3; ++k) {
            int ch = k * 4 + g;
            float mean = statsim[ch * SP] * cnt;
            float var  = statsim[(12 + ch) * SP] * cnt - mean * mean;
            float A = simg[ch] * rsqrtf(var + EPS);
            A3[k] = A;
            Cst += simb[ch] - mean * A;
        }
        Aqk = A3[0]; Aqe = A3[1]; Ake = A3[2];
    }
    int ib = (i0 + g4 * 4) * 2;
    #pragma unroll
    for (int tj = 0; tj < 8; ++tj) {
        int j = tj * 16 + l15;
        h4 q4 = *(const h4*)(L + L_QEA + j * 256 + (ib ^ ((j & 7) << 4)));
        h4 k4 = *(const h4*)(L + L_KEB + j * 256 + (ib ^ ((j & 7) << 4)));
        #pragma unroll
        for (int r = 0; r < 4; ++r)
            acc[tj][r] = Aqk * acc[tj][r] + Aqe * (float)q4[r] + Ake * (float)k4[r] + Cst;
    }

    float inv4[4];
    #pragma unroll
    for (int r = 0; r < 4; ++r) {
        float m = acc[0][r];
        #pragma unroll
        for (int tj = 1; tj < 8; ++tj) m = fmaxf(m, acc[tj][r]);
        #pragma unroll
        for (int msk = 1; msk < 16; msk <<= 1) m = fmaxf(m, __shfl_xor(m, msk, 64));
        float s = 0.f;
        #pragma unroll
        for (int tj = 0; tj < 8; ++tj) {
            float e = __expf(acc[tj][r] - m);
            acc[tj][r] = e; s += e;
        }
        #pragma unroll
        for (int msk = 1; msk < 16; msk <<= 1) s += __shfl_xor(s, msk, 64);
        inv4[r] = 1.f / s;
    }
    __syncthreads();

    #pragma unroll
    for (int r = 0; r < 4; ++r) {
        int i = i0 + g4 * 4 + r;
        int swz = (i & 7) << 4;
        float inv = inv4[r];
        #pragma unroll
        for (int tj = 0; tj < 8; ++tj) {
            int j = tj * 16 + l15;
            _Float16 h = (_Float16)(acc[tj][r] * inv);
            *(_Float16*)(L + L_QEA + i * 256 + ((j * 2) ^ swz)) = h;
            int cl = (j >= i) ? (127 + i - j) : j;
            *(_Float16*)(L + L_KEB + i * 256 + ((cl * 2) ^ swz)) = (j >= i) ? h : (_Float16)0.f;
        }
    }
    __syncthreads();

    h8 vf[4], vef[4];
    #pragma unroll
    for (int ks = 0; ks < 4; ++ks) {
        vf[ks]  = *(const h8*)(L + L_V   + l15 * 256 + ((ks * 64 + g4 * 16) ^ ((l15 & 7) << 4)));
        vef[ks] = *(const h8*)(L + L_RET + l15 * 512 + ((ks * 64 + g4 * 16) ^ ((l15 & 7) << 4)));
    }
    int row = i0 + l15;
    int sw = (row & 7) << 4;
    f4 cam = {0.f, 0.f, 0.f, 0.f}, cae = {0.f, 0.f, 0.f, 0.f};
    #pragma unroll
    for (int ks = 0; ks < 4; ++ks) {
        h8 pf  = *(const h8*)(L + L_QEA + row * 256 + ((ks * 64 + g4 * 16) ^ sw));
        h8 plf = *(const h8*)(L + L_KEB + row * 256 + ((ks * 64 + g4 * 16) ^ sw));
        cam = __builtin_amdgcn_mfma_f32_16x16x32_f16(vf[ks],  pf,  cam, 0, 0, 0);
        cae = __builtin_amdgcn_mfma_f32_16x16x32_f16(vef[ks], plf, cae, 0, 0, 0);
    }
    __syncthreads();

    #pragma unroll
    for (int r = 0; r < 4; ++r) {
        int i = i0 + g4 * 4 + r;
        int swz = (i & 7) << 4;
        float inv = inv4[r];
        #pragma unroll
        for (int tj = 0; tj < 8; ++tj) {
            int j = tj * 16 + l15;
            _Float16 h = (_Float16)(acc[tj][r] * inv);
            int cl = (j < i) ? (i - 1 - j) : j;
            *(_Float16*)(L + L_KEB + i * 256 + ((cl * 2) ^ swz)) = (j < i) ? h : (_Float16)0.f;
        }
    }
    __syncthreads();

    h8 vef2[4];
    #pragma unroll
    for (int ks = 0; ks < 4; ++ks)
        vef2[ks] = *(const h8*)(L + L_RET + l15 * 512 + ((256 + ks * 64 + g4 * 16) ^ ((l15 & 7) << 4)));
    #pragma unroll
    for (int ks = 0; ks < 4; ++ks) {
        h8 phf = *(const h8*)(L + L_KEB + row * 256 + ((ks * 64 + g4 * 16) ^ sw));
        cae = __builtin_amdgcn_mfma_f32_16x16x32_f16(vef2[ks], phf, cae, 0, 0, 0);
    }

    unsigned int* ab = att2 + n * 8192 + (g * 16) * 128;
    int i = i0 + l15;
    #pragma unroll
    for (int r = 0; r < 4; ++r) {
        int c = g4 * 4 + r;
        union { _Float16 h[2]; unsigned int u; } pk;
        pk.h[0] = (_Float16)cam[r];
        pk.h[1] = (_Float16)cae[r];
        ab[c * 128 + i] = pk.u;
    }

    float* sred = (float*)(L + L_QEA);
    #pragma unroll
    for (int r = 0; r < 4; ++r) {
        float sa = cam[r], qa = cam[r] * cam[r];
        float se = cae[r], qe = cae[r] * cae[r];
        #pragma unroll
        for (int msk = 1; msk < 16; msk <<= 1) {
            sa += __shfl_xor(sa, msk, 64); qa += __shfl_xor(qa, msk, 64);
            se += __shfl_xor(se, msk, 64); qe += __shfl_xor(qe, msk, 64);
        }
        if (l15 == 0) {
            int base = w * 64 + g4 * 16 + r * 4;
            sred[base + 0] = sa; sred[base + 1] = qa;
            sred[base + 2] = se; sred[base + 3] = qe;
        }
    }
    __syncthreads();
    if (t < 64) {
        int lc = t & 31, stat = t >> 5;
        int c = lc >> 1, s = lc & 1;
        int gg4 = c >> 2, r = c & 3;
        float v = 0.f;
        #pragma unroll
        for (int ww = 0; ww < 8; ++ww)
            v += sred[ww * 64 + gg4 * 16 + r * 4 + 2 * s + stat];
        atomicAdd(&statout[(stat * 128 + g * 32 + lc) * SP], v);
    }
}

// axial0 finish
__global__ __launch_bounds__(256) void k_finish0(const unsigned int* __restrict__ att2,
                                                 const float* __restrict__ statout,
                                                 const float* __restrict__ og,
                                                 const float* __restrict__ ob,
                                                 float* __restrict__ t2) {
    __shared__ float tile[8][32][33];
    __shared__ float cf[256];
    int t = threadIdx.x;
    if (t < 128) {
        float mean = statout[t * SP] * (1.f / 65536.f);
        float var  = statout[(128 + t) * SP] * (1.f / 65536.f) - mean * mean;
        float A = og[t] * rsqrtf(var + EPS);
        cf[t] = A;
        cf[128 + t] = ob[t] - mean * A;
    }
    __syncthreads();
    int bid = blockIdx.x;
    int wt = bid & 3, ht = (bid >> 2) & 3, cg = (bid >> 4) & 7, b = bid >> 7;
    for (int i = t; i < 8192; i += 256) {
        int h = i & 31, w = (i >> 5) & 31, cl = i >> 10;
        int c_out = cg * 8 + cl;
        int chg = (c_out >> 4) * 32 + (c_out & 15) * 2;
        int p = chg >> 1;
        union { unsigned int u; _Float16 h2[2]; } pk;
        pk.u = att2[((b * 128 + wt * 32 + w) * 64 + p) * 128 + ht * 32 + h];
        tile[cl][w][h] = cf[chg] * (float)pk.h2[0] + cf[128 + chg]
                       + cf[chg + 1] * (float)pk.h2[1] + cf[129 + chg];
    }
    __syncthreads();
    for (int i = t; i < 8192; i += 256) {
        int w = i & 31, h = (i >> 5) & 31, cl = i >> 10;
        t2[((b * 64 + cg * 8 + cl) * 128 + ht * 32 + h) * 128 + wt * 32 + w] = tile[cl][w][h];
    }
}

// axial1 finish
__global__ __launch_bounds__(256) void k_finish1(const unsigned int* __restrict__ att2,
                                                 const float* __restrict__ statout,
                                                 const float* __restrict__ og,
                                                 const float* __restrict__ ob,
                                                 float* __restrict__ t3) {
    int idx = blockIdx.x * 256 + threadIdx.x;
    int w = idx & 127, h = (idx >> 7) & 127, c = (idx >> 14) & 63, b = idx >> 20;
    int p = (c >> 4) * 16 + (c & 15);
    int chg = 2 * p;
    float m0 = statout[chg * SP] * (1.f / 65536.f);
    float v0_ = statout[(128 + chg) * SP] * (1.f / 65536.f) - m0 * m0;
    float A0 = og[chg] * rsqrtf(v0_ + EPS);
    float B0 = ob[chg] - m0 * A0;
    float m1 = statout[(chg + 1) * SP] * (1.f / 65536.f);
    float v1_ = statout[(129 + chg) * SP] * (1.f / 65536.f) - m1 * m1;
    float A1 = og[chg + 1] * rsqrtf(v1_ + EPS);
    float B1 = ob[chg + 1] - m1 * A1;
    union { unsigned int u; _Float16 h2[2]; } pk;
    pk.u = att2[((b * 128 + h) * 64 + p) * 128 + w];
    t3[idx] = A0 * (float)pk.h2[0] + B0 + A1 * (float)pk.h2[1] + B1;
}

__global__ __launch_bounds__(256) void k_conv2(const float* __restrict__ t3,
                                               const float* __restrict__ w,
                                               float* __restrict__ out) {
    __shared__ float ws_[4096];
    int t = threadIdx.x;
    for (int i = t; i < 4096; i += 256) ws_[i] = w[i];
    __syncthreads();
    int p = blockIdx.x * 256 + t;
    int b = p >> 12, yx = p & 4095, y = yx >> 6, x = yx & 63;
    const float* tp = t3 + b * 1048576 + (2 * y) * 128 + 2 * x;
    float xc[64];
    #pragma unroll
    for (int c = 0; c < 64; ++c) {
        const float* q = tp + c * 16384;
        xc[c] = 0.25f * (q[0] + q[1] + q[128] + q[129]);
    }
    float* op = out + b * 262144 + yx;
    for (int o = 0; o < 64; ++o) {
        float acc = 0.f;
        #pragma unroll
        for (int c = 0; c < 64; ++c) acc += ws_[o * 64 + c] * xc[c];
        op[o * 4096] = acc;
    }
}

__global__ __launch_bounds__(256) void k_final(const float* __restrict__ c2out,
                                               const float* __restrict__ input,
                                               const float* __restrict__ ws,
                                               const float* __restrict__ g2,
                                               const float* __restrict__ b2,
                                               const float* __restrict__ prelu2,
                                               float* __restrict__ out) {
    int idx = blockIdx.x * 256 + threadIdx.x;
    int x = idx & 63, y = (idx >> 6) & 63, o = (idx >> 12) & 63, b = idx >> 18;
    float mean = ws[WS_STAT_C2 + o * SP] * (1.f / 16384.f);
    float var  = ws[WS_STAT_C2 + (64 + o) * SP] * (1.f / 16384.f) - mean * mean;
    float ab = g2[o] * rsqrtf(var + EPS);
    float sc = ws[WS_SB2 + o], bi = ws[WS_SB2 + 64 + o];
    float A = sc * ab;
    float B = sc * (b2[o] - mean * ab) + bi;
    float v = A * c2out[idx] + B;
    const float* ip = input + ((b * 64 + o) * 128 + 2 * y) * 128 + 2 * x;
    v += 0.25f * (ip[0] + ip[1] + ip[128] + ip[129]);
    float s = *prelu2;
    out[idx] = v >= 0.f ? v : s * v;
}

extern "C" void kernel_launch(void* const* d_in, const int* in_sizes, int n_in,
                              void* d_out, int out_size, void* d_ws, size_t ws_size,
                              hipStream_t stream) {
    const float* input    = (const float*)d_in[0];
    const float* latent   = (const float*)d_in[1];
    const float* w_in     = (const float*)d_in[2];
    const float* cbn1_g   = (const float*)d_in[3];
    const float* cbn1_b   = (const float*)d_in[4];
    const float* cbn1_lin = (const float*)d_in[5];
    const float* prelu1   = (const float*)d_in[6];
    const float* ax_qkv_w[2] = {(const float*)d_in[7],  (const float*)d_in[15]};
    const float* ax_qkv_g[2] = {(const float*)d_in[8],  (const float*)d_in[16]};
    const float* ax_qkv_b[2] = {(const float*)d_in[9],  (const float*)d_in[17]};
    const float* ax_sim_g[2] = {(const float*)d_in[10], (const float*)d_in[18]};
    const float* ax_sim_b[2] = {(const float*)d_in[11], (const float*)d_in[19]};
    const float* ax_rel[2]   = {(const float*)d_in[12], (const float*)d_in[20]};
    const float* ax_out_g[2] = {(const float*)d_in[13], (const float*)d_in[21]};
    const float* ax_out_b[2] = {(const float*)d_in[14], (const float*)d_in[22]};
    const float* w_out    = (const float*)d_in[23];
    const float* cbn2_g   = (const float*)d_in[24];
    const float* cbn2_b   = (const float*)d_in[25];
    const float* cbn2_lin = (const float*)d_in[26];
    const float* prelu2   = (const float*)d_in[27];

    float* ws    = (float*)d_ws;
    float* out0  = ws + WS_R1;
    float* t1t   = ws + WS_R1 + 4194304;
    unsigned int* att2 = (unsigned int*)(ws + WS_R1);
    float* c2o   = ws + WS_R1;
    _Float16* qkvh = (_Float16*)(ws + WS_R2);
    float* t23   = ws + WS_R3;
    float* dst   = (float*)d_out;

    k_prep0<<<1, 256, 0, stream>>>(cbn1_lin, cbn2_lin, latent, ws);
    k_conv1<<<256, 256, 0, stream>>>(input, w_in, out0);
    k_stats<<<1024, 256, 0, stream>>>(out0, 64, 14, 65536, 16, ws + WS_STAT_C1);
    k_t1t<<<4096, 256, 0, stream>>>(out0, t1t, ws, cbn1_g, cbn1_b, prelu1);

    // axial 0 (n = b*128 + w, a = h)
    k_qkvm<<<512, 256, 0, stream>>>(t1t, ax_qkv_w[0], qkvh, 1048576, 8192, 128);
    k_stats_h<<<1024, 256, 0, stream>>>(qkvh, 128, 7, 65536, 8, ws + WS_STAT_QKV0);
    k_passA<<<2048, 512, 0, stream>>>(qkvh, ax_rel[0], ws + WS_STAT_QKV0,
                                      ax_qkv_g[0], ax_qkv_b[0], ws + WS_STAT_SIM0);
    k_passB<<<2048, 512, 0, stream>>>(qkvh, ax_rel[0], ws + WS_STAT_QKV0,
                                      ax_qkv_g[0], ax_qkv_b[0], ws + WS_STAT_SIM0,
                                      ax_sim_g[0], ax_sim_b[0], att2, ws + WS_STAT_OUT0);
    k_finish0<<<512, 256, 0, stream>>>(att2, ws + WS_STAT_OUT0, ax_out_g[0], ax_out_b[0], t23);

    // axial 1 (n = b*128 + h, a = w)
    k_qkvm<<<512, 256, 0, stream>>>(t23, ax_qkv_w[1], qkvh, 1048576, 128, 16384);
    k_stats_h<<<1024, 256, 0, stream>>>(qkvh, 128, 7, 65536, 8, ws + WS_STAT_QKV1);
    k_passA<<<2048, 512, 0, stream>>>(qkvh, ax_rel[1], ws + WS_STAT_QKV1,
                                      ax_qkv_g[1], ax_qkv_b[1], ws + WS_STAT_SIM1);
    k_passB<<<2048, 512, 0, stream>>>(qkvh, ax_rel[1], ws + WS_STAT_QKV1,
                                      ax_qkv_g[1], ax_qkv_b[1], ws + WS_STAT_SIM1,
                                      ax_sim_g[1], ax_sim_b[1], att2, ws + WS_STAT_OUT1);
    k_finish1<<<16384, 256, 0, stream>>>(att2, ws + WS_STAT_OUT1, ax_out_g[1], ax_out_b[1], t23);

    k_conv2<<<64, 256, 0, stream>>>(t23, w_out, c2o);
    k_stats<<<256, 256, 0, stream>>>(c2o, 64, 12, 16384, 4, ws + WS_STAT_C2);
    k_final<<<4096, 256, 0, stream>>>(c2o, input, ws, cbn2_g, cbn2_b, prelu2, dst);
}

// Round 8
// 405.845 us; speedup vs baseline: 2.4277x; 1.0188x over previous
//
#include <hip/hip_runtime.h>

#define EPS 1e-5f
#define SP 16   // stat padding stride: one float per 64B line

typedef __attribute__((ext_vector_type(4))) _Float16 h4;
typedef __attribute__((ext_vector_type(8))) _Float16 h8;
typedef __attribute__((ext_vector_type(4))) float f4;
typedef __attribute__((ext_vector_type(4))) unsigned int u4;

// ---- workspace float offsets. Stat arrays are SP-strided.
#define WS_SB1        0
#define WS_SB2        128
#define WS_STAT_C1    256
#define WS_STAT_QKV0  2304
#define WS_STAT_QKV1  6400
#define WS_STAT_SIM0  10496
#define WS_STAT_SIM1  10880
#define WS_STAT_OUT0  11264
#define WS_STAT_OUT1  15360
#define WS_STAT_C2    19456
#define WS_STAT_END   21504

// ---- buffer regions (float offsets) ----
#define WS_R1  32768
#define WS_R2  (WS_R1 + 8388608)
#define WS_R3  (WS_R2 + 8388608)

// ---- pass-kernel LDS byte offsets (80 KiB -> 2 blocks/CU) ----
#define L_QEA 0
#define L_KEB 32768
#define L_RET 65536
#define L_AQ  73728
#define L_AK  77824
#define L_V   73728

__device__ __forceinline__ float wred(float v) {
    #pragma unroll
    for (int off = 32; off > 0; off >>= 1) v += __shfl_down(v, off, 64);
    return v;
}

__global__ void k_prep0(const float* __restrict__ lin1, const float* __restrict__ lin2,
                        const float* __restrict__ latent, float* __restrict__ ws) {
    int t = threadIdx.x;
    for (int i = 256 + t; i < WS_STAT_END; i += 256) ws[i] = 0.f;
    const float* lin = (t < 128) ? lin1 : lin2;
    int row = t & 127;
    float s = 0.f;
    for (int l = 0; l < 256; ++l) s += lin[row * 256 + l] * latent[l];
    ws[(t < 128 ? WS_SB1 : WS_SB2) + row] = s;
}

__global__ __launch_bounds__(256) void k_conv1(const float* __restrict__ in,
                                               const float* __restrict__ w,
                                               float* __restrict__ out) {
    __shared__ float ws_[4096];
    int t = threadIdx.x;
    for (int i = t; i < 4096; i += 256) ws_[i] = w[i];
    __syncthreads();
    int p  = blockIdx.x * 256 + t;
    int b  = p >> 14, hw = p & 16383;
    const float* ip = in + b * 64 * 16384 + hw;
    float x[64];
    #pragma unroll
    for (int c = 0; c < 64; ++c) x[c] = ip[c * 16384];
    float* op = out + b * 64 * 16384 + hw;
    for (int o = 0; o < 64; ++o) {
        float acc = 0.f;
        #pragma unroll
        for (int c = 0; c < 64; ++c) acc += ws_[o * 64 + c] * x[c];
        op[o * 16384] = acc;
    }
}

// f32 per-channel stats over [M][C][K]; SP-strided output
__global__ void k_stats(const float* __restrict__ src, int C, int logK, int MK, int split,
                        float* __restrict__ stat) {
    int c = blockIdx.x % C;
    int chunk = blockIdx.x / C;
    int per = MK / split;
    int base = chunk * per;
    int Km1 = (1 << logK) - 1;
    float s = 0.f, ss = 0.f;
    for (int i = base + threadIdx.x; i < base + per; i += blockDim.x) {
        int m = i >> logK, k = i & Km1;
        float v = src[((m * C + c) << logK) + k];
        s += v; ss += v * v;
    }
    s = wred(s); ss = wred(ss);
    if ((threadIdx.x & 63) == 0) { atomicAdd(&stat[c * SP], s); atomicAdd(&stat[(C + c) * SP], ss); }
}

// fp16 per-channel stats, qkv-specific (C=128, K=128, 8 chunks); XCD-aligned:
// chunk = bid&7 so XCD x reads n in [x*64, x*64+64) — matches k_qkvm writer.
__global__ void k_stats_h(const _Float16* __restrict__ src, float* __restrict__ stat) {
    int c = blockIdx.x >> 3;
    int chunk = blockIdx.x & 7;
    int base = chunk * 8192;
    float s = 0.f, ss = 0.f;
    for (int i = base + threadIdx.x; i < base + 8192; i += blockDim.x) {
        int m = i >> 7, k = i & 127;
        float v = (float)src[((m * 128 + c) << 7) + k];
        s += v; ss += v * v;
    }
    s = wred(s); ss = wred(ss);
    if ((threadIdx.x & 63) == 0) { atomicAdd(&stat[c * SP], s); atomicAdd(&stat[(128 + c) * SP], ss); }
}

// out0[b][c][h][w] -> t1t[b][w][c][h], inline cbn1 coef + prelu
__global__ __launch_bounds__(256) void k_t1t(const float* __restrict__ src, float* __restrict__ dst,
                                             const float* __restrict__ ws,
                                             const float* __restrict__ g1,
                                             const float* __restrict__ b1,
                                             const float* __restrict__ prelu1) {
    __shared__ float tile[32][33];
    int bid = blockIdx.x;
    int wt = bid & 3, ht = (bid >> 2) & 3, c = (bid >> 4) & 63, b = bid >> 10;
    float mean = ws[WS_STAT_C1 + c * SP] * (1.f / 65536.f);
    float var  = ws[WS_STAT_C1 + (64 + c) * SP] * (1.f / 65536.f) - mean * mean;
    float ab = g1[c] * rsqrtf(var + EPS);
    float sc = ws[WS_SB1 + c], bi = ws[WS_SB1 + 64 + c];
    float A = sc * ab;
    float Bb = sc * (b1[c] - mean * ab) + bi;
    float slope = *prelu1;
    int tx = threadIdx.x & 31, ty = threadIdx.x >> 5;
    const float* sp = src + ((b * 64 + c) * 128 + ht * 32) * 128 + wt * 32;
    for (int r = 0; r < 4; ++r) {
        float v = sp[(ty + r * 8) * 128 + tx];
        v = A * v + Bb;
        v = v >= 0.f ? v : slope * v;
        tile[ty + r * 8][tx] = v;
    }
    __syncthreads();
    float* dp = dst + b * 1048576 + (wt * 32) * 8192 + c * 128 + ht * 32;
    for (int r = 0; r < 4; ++r)
        dp[(ty + r * 8) * 8192 + tx] = tile[tx][ty + r * 8];
}

// MFMA qkv GEMM; XCD-swizzled n so qkv[n] lives on XCD n/64's L2
__global__ __launch_bounds__(256) void k_qkvm(const float* __restrict__ x, const float* __restrict__ w,
                                              _Float16* __restrict__ out,
                                              int SB, int SR, int SC) {
    __shared__ __align__(16) _Float16 Wh[8192];
    __shared__ __align__(16) _Float16 Xt[8192];
    int t = threadIdx.x;
    int lane = t & 63, wv = t >> 6;
    int l15 = lane & 15, g4 = lane >> 4;
    int n = (blockIdx.x & 7) * 64 + (blockIdx.x >> 3);   // XCD swizzle (512 blocks)
    int b = n >> 7, r = n & 127;
    for (int i = t; i < 8192; i += 256) {
        int o = i >> 6, c = i & 63;
        Wh[o * 64 + (c ^ ((o & 7) << 3))] = (_Float16)w[i];
    }
    const float* xp = x + b * SB + r * SR;
    for (int i = t; i < 8192; i += 256) {
        int c = i >> 7, a = i & 127;
        Xt[a * 64 + (c ^ ((a & 7) << 3))] = (_Float16)xp[c * SC + a];
    }
    __syncthreads();
    _Float16* op = out + n * 16384;
    #pragma unroll
    for (int ot2 = 0; ot2 < 2; ++ot2) {
        int orow = (wv * 2 + ot2) * 16 + l15;
        h8 af[2];
        #pragma unroll
        for (int kk = 0; kk < 2; ++kk)
            af[kk] = *(const h8*)&Wh[orow * 64 + ((kk * 32 + g4 * 8) ^ ((orow & 7) << 3))];
        #pragma unroll
        for (int at = 0; at < 8; ++at) {
            int arow = at * 16 + l15;
            f4 c4 = {0.f, 0.f, 0.f, 0.f};
            #pragma unroll
            for (int kk = 0; kk < 2; ++kk) {
                h8 bf = *(const h8*)&Xt[arow * 64 + ((kk * 32 + g4 * 8) ^ ((arow & 7) << 3))];
                c4 = __builtin_amdgcn_mfma_f32_16x16x32_f16(af[kk], bf, c4, 0, 0, 0);
            }
            #pragma unroll
            for (int r4 = 0; r4 < 4; ++r4) {
                int o = (wv * 2 + ot2) * 16 + g4 * 4 + r4;
                op[o * 128 + at * 16 + l15] = (_Float16)c4[r4];
            }
        }
    }
}

// ---- pass helpers (512 threads) ----
__device__ __forceinline__ void stage_aqk(unsigned char* L, const _Float16* qkv,
                                          const float* statq, const float* qg, const float* qb,
                                          int n, int g, int t) {
    const _Float16* qp = qkv + n * 16384 + g * 32 * 128;
    #pragma unroll
    for (int k = 0; k < 4; ++k) {
        int i = t + k * 512;
        int a = i & 127, cc = i >> 7;
        int ch = g * 32 + cc;
        float mean = statq[ch * SP] * (1.f / 65536.f);
        float var  = statq[(128 + ch) * SP] * (1.f / 65536.f) - mean * mean;
        float A = qg[ch] * rsqrtf(var + EPS);
        float B = qb[ch] - mean * A;
        float v = A * (float)qp[cc * 128 + a] + B;
        _Float16 h = (_Float16)v;
        int off = a * 32 + ((cc * 2) ^ ((a & 4) << 2));
        *(_Float16*)(L + L_AQ + off) = (cc < 8) ? h : (_Float16)0.f;
        *(_Float16*)(L + L_AK + off) = (cc < 8) ? (_Float16)0.f : h;
    }
}

__device__ __forceinline__ void stage_ret(unsigned char* L, const float* remb, int crow0, int t) {
    #pragma unroll
    for (int k = 0; k < 8; ++k) {
        int i = t + k * 512;
        int d = i & 255, c = i >> 8;
        float v = (d < 255) ? remb[(crow0 + c) * 255 + d] : 0.f;
        *(_Float16*)(L + L_RET + d * 32 + ((c * 2) ^ ((d & 4) << 2))) = (_Float16)v;
    }
}

template <bool STATS>
__device__ __forceinline__ void build_emb(unsigned char* L, int w, int l15, int g4, float* s) {
    int at = w;
    int arow = at * 16 + l15;
    int aoff = arow * 32 + ((g4 * 8) ^ ((arow & 4) << 2));
    h4 aq = *(const h4*)(L + L_AQ + aoff);
    h4 ak = *(const h4*)(L + L_AK + aoff);
    int abase = at * 16 + g4 * 4;
    #pragma unroll
    for (int m = 0; m < 9; ++m) {
        int drow = (at + m) * 16 + l15;
        h4 bf = *(const h4*)(L + L_RET + drow * 32 + ((g4 * 8) ^ ((drow & 4) << 2)));
        f4 z = {0.f, 0.f, 0.f, 0.f};
        f4 dq = __builtin_amdgcn_mfma_f32_16x16x16f16(aq, bf, z, 0, 0, 0);
        f4 dk = __builtin_amdgcn_mfma_f32_16x16x16f16(ak, bf, z, 0, 0, 0);
        #pragma unroll
        for (int r = 0; r < 4; ++r) {
            int a = abase + r;
            int b = 127 + a - drow;
            bool ok = (m == 0 || m == 8) ? (b >= 0 && b < 128) : true;
            if (ok) {
                int off = b * 256 + ((a * 2) ^ ((b & 7) << 4));
                *(_Float16*)(L + L_QEA + off) = (_Float16)dq[r];
                *(_Float16*)(L + L_KEB + off) = (_Float16)dk[r];
                if (STATS) {
                    s[0] += dq[r]; s[1] += dq[r] * dq[r];
                    s[2] += dk[r]; s[3] += dk[r] * dk[r];
                }
            }
        }
    }
}

__device__ __forceinline__ void qk_mfma(unsigned char* L, int i0, int l15, int g4, f4 acc[8]) {
    h8 af[4];
    #pragma unroll
    for (int ks = 0; ks < 4; ++ks) {
        int row = i0 + l15;
        af[ks] = *(const h8*)(L + L_QEA + row * 256 + ((ks * 64 + g4 * 16) ^ ((row & 7) << 4)));
    }
    #pragma unroll
    for (int tj = 0; tj < 8; ++tj) {
        h8 bf[4];
        #pragma unroll
        for (int ks = 0; ks < 4; ++ks) {
            int row = tj * 16 + l15;
            bf[ks] = *(const h8*)(L + L_KEB + row * 256 + ((ks * 64 + g4 * 16) ^ ((row & 7) << 4)));
        }
        f4 c = {0.f, 0.f, 0.f, 0.f};
        #pragma unroll
        for (int ks = 0; ks < 4; ++ks)
            c = __builtin_amdgcn_mfma_f32_16x16x32_f16(af[ks], bf[ks], c, 0, 0, 0);
        acc[tj] = c;
    }
}

__global__ __launch_bounds__(512, 4) void k_passA(const _Float16* __restrict__ qkv,
                                                  const float* __restrict__ remb,
                                                  const float* __restrict__ statq,
                                                  const float* __restrict__ qg,
                                                  const float* __restrict__ qb,
                                                  float* __restrict__ statsim) {
    __shared__ __align__(16) unsigned char L[81920];
    int t = threadIdx.x;
    int lane = t & 63, w = t >> 6;
    int l15 = lane & 15, g4 = lane >> 4;
    int s0 = (blockIdx.x & 7) * 256 + (blockIdx.x >> 3);   // XCD swizzle (2048 blocks)
    int n = s0 >> 2, g = s0 & 3;

    stage_aqk(L, qkv, statq, qg, qb, n, g, t);
    stage_ret(L, remb, 0, t);
    __syncthreads();

    float es[4] = {0.f, 0.f, 0.f, 0.f};
    build_emb<true>(L, w, l15, g4, es);
    __syncthreads();

    float* red = (float*)(L + L_AK);
    #pragma unroll
    for (int k = 0; k < 4; ++k) es[k] = wred(es[k]);
    if (lane == 0) {
        red[w * 4 + 0] = es[0]; red[w * 4 + 1] = es[1];
        red[w * 4 + 2] = es[2]; red[w * 4 + 3] = es[3];
    }

    f4 acc[8];
    qk_mfma(L, w * 16, l15, g4, acc);

    float s = 0.f, ss = 0.f;
    #pragma unroll
    for (int tj = 0; tj < 8; ++tj)
        #pragma unroll
        for (int r = 0; r < 4; ++r) { float x = acc[tj][r]; s += x; ss += x * x; }
    s = wred(s); ss = wred(ss);
    if (lane == 0) { red[32 + w * 2] = s; red[33 + w * 2] = ss; }
    __syncthreads();

    if (t < 6) {
        float v = 0.f;
        int dst;
        if (t == 0)      { for (int k = 0; k < 8; ++k) v += red[32 + 2 * k]; dst = g; }
        else if (t == 1) { for (int k = 0; k < 8; ++k) v += red[33 + 2 * k]; dst = 12 + g; }
        else if (t == 2) { for (int k = 0; k < 8; ++k) v += red[k * 4 + 0];  dst = 4 + g; }
        else if (t == 3) { for (int k = 0; k < 8; ++k) v += red[k * 4 + 1];  dst = 16 + g; }
        else if (t == 4) { for (int k = 0; k < 8; ++k) v += red[k * 4 + 2];  dst = 8 + g; }
        else             { for (int k = 0; k < 8; ++k) v += red[k * 4 + 3];  dst = 20 + g; }
        atomicAdd(&statsim[dst * SP], v);
    }
}

// passB: rebuild, combine+softmax, am+ame MFMA, LDS-staged coalesced att store, fused out-stats
__global__ __launch_bounds__(512, 4) void k_passB(const _Float16* __restrict__ qkv,
                                                  const float* __restrict__ remb,
                                                  const float* __restrict__ statq,
                                                  const float* __restrict__ qg,
                                                  const float* __restrict__ qb,
                                                  const float* __restrict__ statsim,
                                                  const float* __restrict__ simg,
                                                  const float* __restrict__ simb,
                                                  unsigned int* __restrict__ att2,
                                                  float* __restrict__ statout) {
    __shared__ __align__(16) unsigned char L[81920];
    int t = threadIdx.x;
    int lane = t & 63, w = t >> 6;
    int l15 = lane & 15, g4 = lane >> 4;
    int s0 = (blockIdx.x & 7) * 256 + (blockIdx.x >> 3);   // XCD swizzle (2048 blocks)
    int n = s0 >> 2, g = s0 & 3;

    stage_aqk(L, qkv, statq, qg, qb, n, g, t);
    stage_ret(L, remb, 0, t);
    __syncthreads();

    build_emb<false>(L, w, l15, g4, nullptr);
    __syncthreads();

    #pragma unroll
    for (int k = 0; k < 4; ++k) {
        int i = t + k * 512;
        int j = i & 127, c = i >> 7;
        int ch = g * 32 + 16 + c;
        float mean = statq[ch * SP] * (1.f / 65536.f);
        float var  = statq[(128 + ch) * SP] * (1.f / 65536.f) - mean * mean;
        float A = qg[ch] * rsqrtf(var + EPS);
        float B = qb[ch] - mean * A;
        float v = A * (float)qkv[n * 16384 + ch * 128 + j] + B;
        *(_Float16*)(L + L_V + c * 256 + ((j * 2) ^ ((c & 7) << 4))) = (_Float16)v;
    }
    #pragma unroll
    for (int k = 0; k < 8; ++k) {
        int i = t + k * 512;
        int d = i & 255, c = i >> 8;
        float v = (d < 255) ? remb[(16 + c) * 255 + d] : 0.f;
        *(_Float16*)(L + L_RET + c * 512 + ((d * 2) ^ ((c & 7) << 4))) = (_Float16)v;
    }

    int i0 = w * 16;
    f4 acc[8];
    qk_mfma(L, i0, l15, g4, acc);

    float Aqk, Aqe, Ake, Cst = 0.f;
    {
        float cnt = 1.f / 8388608.f;
        float A3[3];
        #pragma unroll
        for (int k = 0; k < 3; ++k) {
            int ch = k * 4 + g;
            float mean = statsim[ch * SP] * cnt;
            float var  = statsim[(12 + ch) * SP] * cnt - mean * mean;
            float A = simg[ch] * rsqrtf(var + EPS);
            A3[k] = A;
            Cst += simb[ch] - mean * A;
        }
        Aqk = A3[0]; Aqe = A3[1]; Ake = A3[2];
    }
    int ib = (i0 + g4 * 4) * 2;
    #pragma unroll
    for (int tj = 0; tj < 8; ++tj) {
        int j = tj * 16 + l15;
        h4 q4 = *(const h4*)(L + L_QEA + j * 256 + (ib ^ ((j & 7) << 4)));
        h4 k4 = *(const h4*)(L + L_KEB + j * 256 + (ib ^ ((j & 7) << 4)));
        #pragma unroll
        for (int r = 0; r < 4; ++r)
            acc[tj][r] = Aqk * acc[tj][r] + Aqe * (float)q4[r] + Ake * (float)k4[r] + Cst;
    }

    float inv4[4];
    #pragma unroll
    for (int r = 0; r < 4; ++r) {
        float m = acc[0][r];
        #pragma unroll
        for (int tj = 1; tj < 8; ++tj) m = fmaxf(m, acc[tj][r]);
        #pragma unroll
        for (int msk = 1; msk < 16; msk <<= 1) m = fmaxf(m, __shfl_xor(m, msk, 64));
        float s = 0.f;
        #pragma unroll
        for (int tj = 0; tj < 8; ++tj) {
            float e = __expf(acc[tj][r] - m);
            acc[tj][r] = e; s += e;
        }
        #pragma unroll
        for (int msk = 1; msk < 16; msk <<= 1) s += __shfl_xor(s, msk, 64);
        inv4[r] = 1.f / s;
    }

    // precompute fp16 P fragments once
    _Float16 ph[4][8];
    #pragma unroll
    for (int r = 0; r < 4; ++r)
        #pragma unroll
        for (int tj = 0; tj < 8; ++tj)
            ph[r][tj] = (_Float16)(acc[tj][r] * inv4[r]);
    __syncthreads();

    #pragma unroll
    for (int r = 0; r < 4; ++r) {
        int i = i0 + g4 * 4 + r;
        int swz = (i & 7) << 4;
        #pragma unroll
        for (int tj = 0; tj < 8; ++tj) {
            int j = tj * 16 + l15;
            _Float16 h = ph[r][tj];
            *(_Float16*)(L + L_QEA + i * 256 + ((j * 2) ^ swz)) = h;
            int cl = (j >= i) ? (127 + i - j) : j;
            *(_Float16*)(L + L_KEB + i * 256 + ((cl * 2) ^ swz)) = (j >= i) ? h : (_Float16)0.f;
        }
    }
    __syncthreads();

    h8 vf[4], vef[4];
    #pragma unroll
    for (int ks = 0; ks < 4; ++ks) {
        vf[ks]  = *(const h8*)(L + L_V   + l15 * 256 + ((ks * 64 + g4 * 16) ^ ((l15 & 7) << 4)));
        vef[ks] = *(const h8*)(L + L_RET + l15 * 512 + ((ks * 64 + g4 * 16) ^ ((l15 & 7) << 4)));
    }
    int row = i0 + l15;
    int sw = (row & 7) << 4;
    f4 cam = {0.f, 0.f, 0.f, 0.f}, cae = {0.f, 0.f, 0.f, 0.f};
    #pragma unroll
    for (int ks = 0; ks < 4; ++ks) {
        h8 pf  = *(const h8*)(L + L_QEA + row * 256 + ((ks * 64 + g4 * 16) ^ sw));
        h8 plf = *(const h8*)(L + L_KEB + row * 256 + ((ks * 64 + g4 * 16) ^ sw));
        cam = __builtin_amdgcn_mfma_f32_16x16x32_f16(vf[ks],  pf,  cam, 0, 0, 0);
        cae = __builtin_amdgcn_mfma_f32_16x16x32_f16(vef[ks], plf, cae, 0, 0, 0);
    }
    __syncthreads();

    #pragma unroll
    for (int r = 0; r < 4; ++r) {
        int i = i0 + g4 * 4 + r;
        int swz = (i & 7) << 4;
        #pragma unroll
        for (int tj = 0; tj < 8; ++tj) {
            int j = tj * 16 + l15;
            int cl = (j < i) ? (i - 1 - j) : j;
            *(_Float16*)(L + L_KEB + i * 256 + ((cl * 2) ^ swz)) = (j < i) ? ph[r][tj] : (_Float16)0.f;
        }
    }
    __syncthreads();

    h8 vef2[4];
    #pragma unroll
    for (int ks = 0; ks < 4; ++ks)
        vef2[ks] = *(const h8*)(L + L_RET + l15 * 512 + ((256 + ks * 64 + g4 * 16) ^ ((l15 & 7) << 4)));
    #pragma unroll
    for (int ks = 0; ks < 4; ++ks) {
        h8 phf = *(const h8*)(L + L_KEB + row * 256 + ((ks * 64 + g4 * 16) ^ sw));
        cae = __builtin_amdgcn_mfma_f32_16x16x32_f16(vef2[ks], phf, cae, 0, 0, 0);
    }

    // stage att tile in LDS (QEA dead), then coalesced full-line copy-out
    unsigned int* attL = (unsigned int*)(L + L_QEA);
    int i = i0 + l15;
    #pragma unroll
    for (int r = 0; r < 4; ++r) {
        union { _Float16 h[2]; unsigned int u; } pk;
        pk.h[0] = (_Float16)cam[r];
        pk.h[1] = (_Float16)cae[r];
        attL[(g4 * 4 + r) * 128 + i] = pk.u;
    }

    // out-BN stats partials (sred in KEB — dead after ame2)
    float* sred = (float*)(L + L_KEB);
    #pragma unroll
    for (int r = 0; r < 4; ++r) {
        float sa = cam[r], qa = cam[r] * cam[r];
        float se = cae[r], qe = cae[r] * cae[r];
        #pragma unroll
        for (int msk = 1; msk < 16; msk <<= 1) {
            sa += __shfl_xor(sa, msk, 64); qa += __shfl_xor(qa, msk, 64);
            se += __shfl_xor(se, msk, 64); qe += __shfl_xor(qe, msk, 64);
        }
        if (l15 == 0) {
            int base = w * 64 + g4 * 16 + r * 4;
            sred[base + 0] = sa; sred[base + 1] = qa;
            sred[base + 2] = se; sred[base + 3] = qe;
        }
    }
    __syncthreads();

    unsigned int* ab = att2 + n * 8192 + g * 2048;
    *(u4*)(ab + t * 4) = *(const u4*)(attL + t * 4);

    if (t < 64) {
        int lc = t & 31, stat = t >> 5;
        int c = lc >> 1, s = lc & 1;
        int gg4 = c >> 2, r = c & 3;
        float v = 0.f;
        #pragma unroll
        for (int ww = 0; ww < 8; ++ww)
            v += sred[ww * 64 + gg4 * 16 + r * 4 + 2 * s + stat];
        atomicAdd(&statout[(stat * 128 + g * 32 + lc) * SP], v);
    }
}

// axial0 finish
__global__ __launch_bounds__(256) void k_finish0(const unsigned int* __restrict__ att2,
                                                 const float* __restrict__ statout,
                                                 const float* __restrict__ og,
                                                 const float* __restrict__ ob,
                                                 float* __restrict__ t2) {
    __shared__ float tile[8][32][33];
    __shared__ float cf[256];
    int t = threadIdx.x;
    if (t < 128) {
        float mean = statout[t * SP] * (1.f / 65536.f);
        float var  = statout[(128 + t) * SP] * (1.f / 65536.f) - mean * mean;
        float A = og[t] * rsqrtf(var + EPS);
        cf[t] = A;
        cf[128 + t] = ob[t] - mean * A;
    }
    __syncthreads();
    int bid = blockIdx.x;
    int wt = bid & 3, ht = (bid >> 2) & 3, cg = (bid >> 4) & 7, b = bid >> 7;
    for (int i = t; i < 8192; i += 256) {
        int h = i & 31, w = (i >> 5) & 31, cl = i >> 10;
        int c_out = cg * 8 + cl;
        int chg = (c_out >> 4) * 32 + (c_out & 15) * 2;
        int p = chg >> 1;
        union { unsigned int u; _Float16 h2[2]; } pk;
        pk.u = att2[((b * 128 + wt * 32 + w) * 64 + p) * 128 + ht * 32 + h];
        tile[cl][w][h] = cf[chg] * (float)pk.h2[0] + cf[128 + chg]
                       + cf[chg + 1] * (float)pk.h2[1] + cf[129 + chg];
    }
    __syncthreads();
    for (int i = t; i < 8192; i += 256) {
        int w = i & 31, h = (i >> 5) & 31, cl = i >> 10;
        t2[((b * 64 + cg * 8 + cl) * 128 + ht * 32 + h) * 128 + wt * 32 + w] = tile[cl][w][h];
    }
}

// axial1 finish
__global__ __launch_bounds__(256) void k_finish1(const unsigned int* __restrict__ att2,
                                                 const float* __restrict__ statout,
                                                 const float* __restrict__ og,
                                                 const float* __restrict__ ob,
                                                 float* __restrict__ t3) {
    int idx = blockIdx.x * 256 + threadIdx.x;
    int w = idx & 127, h = (idx >> 7) & 127, c = (idx >> 14) & 63, b = idx >> 20;
    int p = (c >> 4) * 16 + (c & 15);
    int chg = 2 * p;
    float m0 = statout[chg * SP] * (1.f / 65536.f);
    float v0_ = statout[(128 + chg) * SP] * (1.f / 65536.f) - m0 * m0;
    float A0 = og[chg] * rsqrtf(v0_ + EPS);
    float B0 = ob[chg] - m0 * A0;
    float m1 = statout[(chg + 1) * SP] * (1.f / 65536.f);
    float v1_ = statout[(129 + chg) * SP] * (1.f / 65536.f) - m1 * m1;
    float A1 = og[chg + 1] * rsqrtf(v1_ + EPS);
    float B1 = ob[chg + 1] - m1 * A1;
    union { unsigned int u; _Float16 h2[2]; } pk;
    pk.u = att2[((b * 128 + h) * 64 + p) * 128 + w];
    t3[idx] = A0 * (float)pk.h2[0] + B0 + A1 * (float)pk.h2[1] + B1;
}

__global__ __launch_bounds__(256) void k_conv2(const float* __restrict__ t3,
                                               const float* __restrict__ w,
                                               float* __restrict__ out) {
    __shared__ float ws_[4096];
    int t = threadIdx.x;
    for (int i = t; i < 4096; i += 256) ws_[i] = w[i];
    __syncthreads();
    int p = blockIdx.x * 256 + t;
    int b = p >> 12, yx = p & 4095, y = yx >> 6, x = yx & 63;
    const float* tp = t3 + b * 1048576 + (2 * y) * 128 + 2 * x;
    float xc[64];
    #pragma unroll
    for (int c = 0; c < 64; ++c) {
        const float* q = tp + c * 16384;
        xc[c] = 0.25f * (q[0] + q[1] + q[128] + q[129]);
    }
    float* op = out + b * 262144 + yx;
    for (int o = 0; o < 64; ++o) {
        float acc = 0.f;
        #pragma unroll
        for (int c = 0; c < 64; ++c) acc += ws_[o * 64 + c] * xc[c];
        op[o * 4096] = acc;
    }
}

__global__ __launch_bounds__(256) void k_final(const float* __restrict__ c2out,
                                               const float* __restrict__ input,
                                               const float* __restrict__ ws,
                                               const float* __restrict__ g2,
                                               const float* __restrict__ b2,
                                               const float* __restrict__ prelu2,
                                               float* __restrict__ out) {
    int idx = blockIdx.x * 256 + threadIdx.x;
    int x = idx & 63, y = (idx >> 6) & 63, o = (idx >> 12) & 63, b = idx >> 18;
    float mean = ws[WS_STAT_C2 + o * SP] * (1.f / 16384.f);
    float var  = ws[WS_STAT_C2 + (64 + o) * SP] * (1.f / 16384.f) - mean * mean;
    float ab = g2[o] * rsqrtf(var + EPS);
    float sc = ws[WS_SB2 + o], bi = ws[WS_SB2 + 64 + o];
    float A = sc * ab;
    float B = sc * (b2[o] - mean * ab) + bi;
    float v = A * c2out[idx] + B;
    const float* ip = input + ((b * 64 + o) * 128 + 2 * y) * 128 + 2 * x;
    v += 0.25f * (ip[0] + ip[1] + ip[128] + ip[129]);
    float s = *prelu2;
    out[idx] = v >= 0.f ? v : s * v;
}

extern "C" void kernel_launch(void* const* d_in, const int* in_sizes, int n_in,
                              void* d_out, int out_size, void* d_ws, size_t ws_size,
                              hipStream_t stream) {
    const float* input    = (const float*)d_in[0];
    const float* latent   = (const float*)d_in[1];
    const float* w_in     = (const float*)d_in[2];
    const float* cbn1_g   = (const float*)d_in[3];
    const float* cbn1_b   = (const float*)d_in[4];
    const float* cbn1_lin = (const float*)d_in[5];
    const float* prelu1   = (const float*)d_in[6];
    const float* ax_qkv_w[2] = {(const float*)d_in[7],  (const float*)d_in[15]};
    const float* ax_qkv_g[2] = {(const float*)d_in[8],  (const float*)d_in[16]};
    const float* ax_qkv_b[2] = {(const float*)d_in[9],  (const float*)d_in[17]};
    const float* ax_sim_g[2] = {(const float*)d_in[10], (const float*)d_in[18]};
    const float* ax_sim_b[2] = {(const float*)d_in[11], (const float*)d_in[19]};
    const float* ax_rel[2]   = {(const float*)d_in[12], (const float*)d_in[20]};
    const float* ax_out_g[2] = {(const float*)d_in[13], (const float*)d_in[21]};
    const float* ax_out_b[2] = {(const float*)d_in[14], (const float*)d_in[22]};
    const float* w_out    = (const float*)d_in[23];
    const float* cbn2_g   = (const float*)d_in[24];
    const float* cbn2_b   = (const float*)d_in[25];
    const float* cbn2_lin = (const float*)d_in[26];
    const float* prelu2   = (const float*)d_in[27];

    float* ws    = (float*)d_ws;
    float* out0  = ws + WS_R1;
    float* t1t   = ws + WS_R1 + 4194304;
    unsigned int* att2 = (unsigned int*)(ws + WS_R1);
    float* c2o   = ws + WS_R1;
    _Float16* qkvh = (_Float16*)(ws + WS_R2);
    float* t23   = ws + WS_R3;
    float* dst   = (float*)d_out;

    k_prep0<<<1, 256, 0, stream>>>(cbn1_lin, cbn2_lin, latent, ws);
    k_conv1<<<256, 256, 0, stream>>>(input, w_in, out0);
    k_stats<<<1024, 256, 0, stream>>>(out0, 64, 14, 65536, 16, ws + WS_STAT_C1);
    k_t1t<<<4096, 256, 0, stream>>>(out0, t1t, ws, cbn1_g, cbn1_b, prelu1);

    // axial 0 (n = b*128 + w, a = h)
    k_qkvm<<<512, 256, 0, stream>>>(t1t, ax_qkv_w[0], qkvh, 1048576, 8192, 128);
    k_stats_h<<<1024, 256, 0, stream>>>(qkvh, ws + WS_STAT_QKV0);
    k_passA<<<2048, 512, 0, stream>>>(qkvh, ax_rel[0], ws + WS_STAT_QKV0,
                                      ax_qkv_g[0], ax_qkv_b[0], ws + WS_STAT_SIM0);
    k_passB<<<2048, 512, 0, stream>>>(qkvh, ax_rel[0], ws + WS_STAT_QKV0,
                                      ax_qkv_g[0], ax_qkv_b[0], ws + WS_STAT_SIM0,
                                      ax_sim_g[0], ax_sim_b[0], att2, ws + WS_STAT_OUT0);
    k_finish0<<<512, 256, 0, stream>>>(att2, ws + WS_STAT_OUT0, ax_out_g[0], ax_out_b[0], t23);

    // axial 1 (n = b*128 + h, a = w)
    k_qkvm<<<512, 256, 0, stream>>>(t23, ax_qkv_w[1], qkvh, 1048576, 128, 16384);
    k_stats_h<<<1024, 256, 0, stream>>>(qkvh, ws + WS_STAT_QKV1);
    k_passA<<<2048, 512, 0, stream>>>(qkvh, ax_rel[1], ws + WS_STAT_QKV1,
                                      ax_qkv_g[1], ax_qkv_b[1], ws + WS_STAT_SIM1);
    k_passB<<<2048, 512, 0, stream>>>(qkvh, ax_rel[1], ws + WS_STAT_QKV1,
                                      ax_qkv_g[1], ax_qkv_b[1], ws + WS_STAT_SIM1,
                                      ax_sim_g[1], ax_sim_b[1], att2, ws + WS_STAT_OUT1);
    k_finish1<<<16384, 256, 0, stream>>>(att2, ws + WS_STAT_OUT1, ax_out_g[1], ax_out_b[1], t23);

    k_conv2<<<64, 256, 0, stream>>>(t23, w_out, c2o);
    k_stats<<<256, 256, 0, stream>>>(c2o, 64, 12, 16384, 4, ws + WS_STAT_C2);
    k_final<<<4096, 256, 0, stream>>>(c2o, input, ws, cbn2_g, cbn2_b, prelu2, dst);
}